// Round 7
// baseline (275.450 us; speedup 1.0000x reference)
//
#include <hip/hip_runtime.h>
#include <hip/hip_bf16.h>
#include <math.h>

#define N_TOK 22506
#define LEN   11253

typedef unsigned short u16;
typedef __attribute__((ext_vector_type(8))) short short8;
typedef __attribute__((ext_vector_type(4))) float f32x4;

#define GLOAD16(g, l) __builtin_amdgcn_global_load_lds( \
    (const __attribute__((address_space(1))) void*)(g), \
    (__attribute__((address_space(3))) void*)(l), 16, 0, 0)

static __device__ __forceinline__ u16 f2bf(float f) {
    unsigned int u = __builtin_bit_cast(unsigned int, f);
    u = (u + 0x7fffu + ((u >> 16) & 1u)) >> 16;
    return (u16)u;
}
static __device__ __forceinline__ float bflo(unsigned int u) {
    return __builtin_bit_cast(float, u << 16);
}
static __device__ __forceinline__ float bfhi(unsigned int u) {
    return __builtin_bit_cast(float, u & 0xffff0000u);
}

// bijective XCD-chunked swizzle (m204)
static __device__ __forceinline__ int xcd_swz(int id, int nwg) {
    int q = nwg >> 3, r = nwg & 7;
    int xcd = id & 7, rank = id >> 3;
    return (xcd < r ? xcd * (q + 1) : r * (q + 1) + (xcd - r) * q) + rank;
}

// ---- weight transposes (f32 -> bf16, [K][N] -> [N][K]) + bias concat ----
__global__ __launch_bounds__(256) void wprep(
    const float* __restrict__ w_value, const float* __restrict__ w_off,
    const float* __restrict__ w_attn, const float* __restrict__ w_out,
    const float* __restrict__ w1, const float* __restrict__ w2,
    const float* __restrict__ b_off, const float* __restrict__ b_attn,
    u16* __restrict__ wv_t, u16* __restrict__ woa_t, u16* __restrict__ wout_t,
    u16* __restrict__ w1_t, u16* __restrict__ w2_t, float* __restrict__ boa)
{
    int i = blockIdx.x * 256 + threadIdx.x;
    if (i < 65536) {
        wv_t[(i & 255) * 256 + (i >> 8)] = f2bf(w_value[i]);
    } else if (i < 131072) {
        int j = i - 65536;
        woa_t[(j & 255) * 256 + (j >> 8)] = f2bf(w_off[j]);
    } else if (i < 163840) {
        int j = i - 131072;
        woa_t[65536 + (j & 127) * 256 + (j >> 7)] = f2bf(w_attn[j]);
    } else if (i < 229376) {
        int j = i - 163840;
        wout_t[(j & 255) * 256 + (j >> 8)] = f2bf(w_out[j]);
    } else if (i < 491520) {
        int j = i - 229376;
        w1_t[(j & 1023) * 256 + (j >> 10)] = f2bf(w1[j]);
    } else if (i < 753664) {
        int j = i - 491520;
        w2_t[(j & 255) * 1024 + (j >> 8)] = f2bf(w2[j]);
    } else if (i < 754048) {
        int j = i - 753664;
        boa[j] = (j < 256) ? b_off[j] : b_attn[j - 256];
    }
}

// ============ B-resident panel GEMM, f32 A (value + off/attn fused) ============
// 512 thr = 8 waves; block = 256 rows x 128 cols, K=256 resident in LDS.
// wave w: rows bm+(w&3)*64, cols pc+(w>>2)*64. No barriers after B load.
__global__ __launch_bounds__(512, 2) void qv_panel(
    const float* __restrict__ src, const float* __restrict__ pos,
    const u16* __restrict__ wv_t, const u16* __restrict__ woa_t,
    const float* __restrict__ b_value, const float* __restrict__ boa,
    u16* __restrict__ Vb, float* __restrict__ OA)
{
    __shared__ u16 Bs[128 * 256];   // 64 KB: [col][256 k-elems, slot-swizzled]
    int tid = threadIdx.x, lane = tid & 63, w = tid >> 6;
    int wr = w & 3, wcp = w >> 2;
    int sid = xcd_swz(blockIdx.x, gridDim.x);
    int p = sid % 5, bm = (sid / 5) * 256;
    int job = p < 2 ? 0 : 1;
    int pc = job ? (p - 2) * 128 : p * 128;
    const u16* Bt = job ? woa_t : wv_t;
    int rlo = lane & 15, khalf = (lane >> 4) & 3;

    const float* srow[4];
    const float* prow[4];
    #pragma unroll
    for (int mi = 0; mi < 4; ++mi) {
        int r = bm + wr * 64 + mi * 16 + rlo;
        r = r < N_TOK ? r : N_TOK - 1;
        srow[mi] = src + (size_t)r * 256 + khalf * 8;
        prow[mi] = pos + (size_t)r * 256 + khalf * 8;
    }

    short8 a0[4], a1[4];
    f32x4 acc[4][4] = {};

    #define QLDA(AR, kf) { \
        _Pragma("unroll") \
        for (int mi = 0; mi < 4; ++mi) { \
            const float* sp = srow[mi] + (kf) * 32; \
            float4 x0 = *(const float4*)sp, x1 = *(const float4*)(sp + 4); \
            if (job) { \
                const float* pp = prow[mi] + (kf) * 32; \
                float4 p0 = *(const float4*)pp, p1 = *(const float4*)(pp + 4); \
                x0.x += p0.x; x0.y += p0.y; x0.z += p0.z; x0.w += p0.w; \
                x1.x += p1.x; x1.y += p1.y; x1.z += p1.z; x1.w += p1.w; \
            } \
            u16 t8[8] = { f2bf(x0.x), f2bf(x0.y), f2bf(x0.z), f2bf(x0.w), \
                          f2bf(x1.x), f2bf(x1.y), f2bf(x1.z), f2bf(x1.w) }; \
            AR[mi] = *(short8*)t8; \
        } }

    QLDA(a0, 0)
    QLDA(a1, 1)
    // stage B panel: 8 x GLOAD16 per thread, inverse-swizzled source
    #pragma unroll
    for (int i = 0; i < 8; ++i) {
        int LI = i * 8192 + tid * 16;
        int col = LI >> 9, sl = (LI >> 4) & 31;
        GLOAD16(Bt + (size_t)(pc + col) * 256 + ((sl ^ (col & 7)) << 3),
                (char*)Bs + i * 8192 + w * 1024);
    }
    __syncthreads();

    #define QSTEP(kf, AR) { \
        short8 bf_[4]; \
        _Pragma("unroll") \
        for (int ni = 0; ni < 4; ++ni) { \
            int c = wcp * 64 + ni * 16 + rlo; \
            bf_[ni] = *(const short8*)(&Bs[(c << 8) + ((((kf) * 4 + khalf) ^ (c & 7)) << 3)]); \
        } \
        _Pragma("unroll") \
        for (int mi = 0; mi < 4; ++mi) \
            _Pragma("unroll") \
            for (int ni = 0; ni < 4; ++ni) \
                acc[mi][ni] = __builtin_amdgcn_mfma_f32_16x16x32_bf16(AR[mi], bf_[ni], acc[mi][ni], 0, 0, 0); \
        if ((kf) + 2 < 8) QLDA(AR, (kf) + 2) }

    QSTEP(0, a0) QSTEP(1, a1) QSTEP(2, a0) QSTEP(3, a1)
    QSTEP(4, a0) QSTEP(5, a1) QSTEP(6, a0) QSTEP(7, a1)
    #undef QSTEP
    #undef QLDA

    int col_l = lane & 15, rgrp = lane >> 4;
    #pragma unroll
    for (int mi = 0; mi < 4; ++mi) {
        #pragma unroll
        for (int j = 0; j < 4; ++j) {
            int row = bm + wr * 64 + mi * 16 + rgrp * 4 + j;
            if (row >= N_TOK) continue;
            #pragma unroll
            for (int ni = 0; ni < 4; ++ni) {
                int col = pc + wcp * 64 + ni * 16 + col_l;
                if (job) OA[(size_t)row * 384 + col] = acc[mi][ni][j] + boa[col];
                else     Vb[(size_t)row * 256 + col] = f2bf(acc[mi][ni][j] + b_value[col]);
            }
        }
    }
}

// ============ B-resident panel GEMM, bf16 A (FFN1) ============
__global__ __launch_bounds__(512, 2) void panel_bf16(
    const u16* __restrict__ A, const u16* __restrict__ Bt,
    const float* __restrict__ bias, u16* __restrict__ Cb,
    int NCout, int npanel)
{
    __shared__ u16 Bs[128 * 256];
    int tid = threadIdx.x, lane = tid & 63, w = tid >> 6;
    int wr = w & 3, wcp = w >> 2;
    int sid = xcd_swz(blockIdx.x, gridDim.x);
    int p = sid % npanel, bm = (sid / npanel) * 256;
    int pc = p * 128;
    int rlo = lane & 15, khalf = (lane >> 4) & 3;

    const u16* arow[4];
    #pragma unroll
    for (int mi = 0; mi < 4; ++mi) {
        int r = bm + wr * 64 + mi * 16 + rlo;
        r = r < N_TOK ? r : N_TOK - 1;
        arow[mi] = A + (size_t)r * 256 + khalf * 8;
    }

    short8 a0[4], a1[4];
    f32x4 acc[4][4] = {};

    #define PLDA(AR, kf) { \
        _Pragma("unroll") \
        for (int mi = 0; mi < 4; ++mi) AR[mi] = *(const short8*)(arow[mi] + (kf) * 32); }

    PLDA(a0, 0)
    PLDA(a1, 1)
    #pragma unroll
    for (int i = 0; i < 8; ++i) {
        int LI = i * 8192 + tid * 16;
        int col = LI >> 9, sl = (LI >> 4) & 31;
        GLOAD16(Bt + (size_t)(pc + col) * 256 + ((sl ^ (col & 7)) << 3),
                (char*)Bs + i * 8192 + w * 1024);
    }
    __syncthreads();

    #define PSTEP(kf, AR) { \
        short8 bf_[4]; \
        _Pragma("unroll") \
        for (int ni = 0; ni < 4; ++ni) { \
            int c = wcp * 64 + ni * 16 + rlo; \
            bf_[ni] = *(const short8*)(&Bs[(c << 8) + ((((kf) * 4 + khalf) ^ (c & 7)) << 3)]); \
        } \
        _Pragma("unroll") \
        for (int mi = 0; mi < 4; ++mi) \
            _Pragma("unroll") \
            for (int ni = 0; ni < 4; ++ni) \
                acc[mi][ni] = __builtin_amdgcn_mfma_f32_16x16x32_bf16(AR[mi], bf_[ni], acc[mi][ni], 0, 0, 0); \
        if ((kf) + 2 < 8) PLDA(AR, (kf) + 2) }

    PSTEP(0, a0) PSTEP(1, a1) PSTEP(2, a0) PSTEP(3, a1)
    PSTEP(4, a0) PSTEP(5, a1) PSTEP(6, a0) PSTEP(7, a1)
    #undef PSTEP
    #undef PLDA

    int col_l = lane & 15, rgrp = lane >> 4;
    #pragma unroll
    for (int mi = 0; mi < 4; ++mi) {
        #pragma unroll
        for (int j = 0; j < 4; ++j) {
            int row = bm + wr * 64 + mi * 16 + rgrp * 4 + j;
            if (row >= N_TOK) continue;
            #pragma unroll
            for (int ni = 0; ni < 4; ++ni) {
                int col = pc + wcp * 64 + ni * 16 + col_l;
                float v = fmaxf(acc[mi][ni][j] + bias[col], 0.f);
                Cb[(size_t)row * NCout + col] = f2bf(v);
            }
        }
    }
}

// ============ full-row GEMM + residual + in-wave LayerNorm ============
// 512 thr = 8 waves; block = 256 rows x ALL 256 cols; K chunked by 256.
// LDS (dynamic 128 KB): 256 cols x 256 k-elems per chunk. Wave owns 32 rows.
__global__ __launch_bounds__(512, 2) void gemm_ln256(
    const u16* __restrict__ A, const u16* __restrict__ Bt,
    const float* __restrict__ bias, const float* __restrict__ res,
    const float* __restrict__ g, const float* __restrict__ beta,
    float* __restrict__ outf, u16* __restrict__ outb, int K, int nchunk)
{
    extern __shared__ u16 BsD[];    // [col][256], slot-swizzled
    int tid = threadIdx.x, lane = tid & 63, w = tid >> 6;
    int sid = xcd_swz(blockIdx.x, gridDim.x);
    int bm = sid * 256;
    int rlo = lane & 15, khalf = (lane >> 4) & 3;

    const u16* arow[2];
    #pragma unroll
    for (int mi = 0; mi < 2; ++mi) {
        int r = bm + w * 32 + mi * 16 + rlo;
        r = r < N_TOK ? r : N_TOK - 1;
        arow[mi] = A + (size_t)r * K + khalf * 8;
    }

    short8 a0[2], a1[2];
    f32x4 acc[2][16] = {};

    #define LLDA(AR, c, kf) { \
        _Pragma("unroll") \
        for (int mi = 0; mi < 2; ++mi) AR[mi] = *(const short8*)(arow[mi] + (c) * 256 + (kf) * 32); }

    for (int c = 0; c < nchunk; ++c) {
        #pragma unroll
        for (int i = 0; i < 16; ++i) {
            int LI = i * 8192 + tid * 16;
            int col = LI >> 9, sl = (LI >> 4) & 31;
            GLOAD16(Bt + (size_t)col * K + c * 256 + ((sl ^ (col & 7)) << 3),
                    (char*)BsD + i * 8192 + w * 1024);
        }
        LLDA(a0, c, 0)
        LLDA(a1, c, 1)
        __syncthreads();

        #define LSTEP(kf, AR) { \
            short8 bf_[16]; \
            _Pragma("unroll") \
            for (int ni = 0; ni < 16; ++ni) { \
                int cc = ni * 16 + rlo; \
                bf_[ni] = *(const short8*)(&BsD[(cc << 8) + ((((kf) * 4 + khalf) ^ (cc & 7)) << 3)]); \
            } \
            _Pragma("unroll") \
            for (int mi = 0; mi < 2; ++mi) \
                _Pragma("unroll") \
                for (int ni = 0; ni < 16; ++ni) \
                    acc[mi][ni] = __builtin_amdgcn_mfma_f32_16x16x32_bf16(AR[mi], bf_[ni], acc[mi][ni], 0, 0, 0); \
            if ((kf) + 2 < 8) LLDA(AR, c, (kf) + 2) }

        LSTEP(0, a0) LSTEP(1, a1) LSTEP(2, a0) LSTEP(3, a1)
        LSTEP(4, a0) LSTEP(5, a1) LSTEP(6, a0) LSTEP(7, a1)
        #undef LSTEP
        __syncthreads();
    }
    #undef LLDA

    // ---- in-wave LayerNorm epilogue (wave owns full 256-col rows) ----
    int col_l = lane & 15, rgrp = lane >> 4;
    #pragma unroll
    for (int mi = 0; mi < 2; ++mi) {
        #pragma unroll
        for (int j = 0; j < 4; ++j) {
            int row = bm + w * 32 + mi * 16 + rgrp * 4 + j;
            int rowc = row < N_TOK ? row : N_TOK - 1;
            float v[16], s = 0.f, s2 = 0.f;
            #pragma unroll
            for (int ni = 0; ni < 16; ++ni) {
                int cc = ni * 16 + col_l;
                float t = acc[mi][ni][j] + bias[cc] + res[(size_t)rowc * 256 + cc];
                v[ni] = t; s += t; s2 += t * t;
            }
            #pragma unroll
            for (int d = 1; d < 16; d <<= 1) { s += __shfl_xor(s, d); s2 += __shfl_xor(s2, d); }
            float mean = s * (1.f / 256.f);
            float var = s2 * (1.f / 256.f) - mean * mean;
            float rs = rsqrtf(var + 1e-5f);
            if (row < N_TOK) {
                #pragma unroll
                for (int ni = 0; ni < 16; ++ni) {
                    int cc = ni * 16 + col_l;
                    float o = g[cc] * (v[ni] - mean) * rs + beta[cc];
                    outf[(size_t)row * 256 + cc] = o;
                    if (outb) outb[(size_t)row * 256 + cc] = f2bf(o);
                }
            }
        }
    }
}

// ---- deformable sampling, phase-split, bf16 value, XOR-permuted LDS ----
__global__ __launch_bounds__(256) void ms_sample(
    const u16* __restrict__ value, const float* __restrict__ oa,
    const float* __restrict__ refp, u16* __restrict__ out)
{
    const int starts[4] = {0, 8464, 10580, 11109};
    const int sizes[4]  = {92, 46, 23, 12};
    int t = threadIdx.x;
    int wv = t >> 6, lane = t & 63;
    int n = blockIdx.x * 4 + wv;

    __shared__ uint4  s_ad[4][128];
    __shared__ float4 s_wt[4][128];

    if (n < N_TOK) {
        const float* oan = oa + (size_t)n * 384;
        unsigned int tokbase = (n >= LEN) ? (unsigned)LEN : 0u;
        #pragma unroll
        for (int rep = 0; rep < 2; ++rep) {
            int q = rep * 64 + lane;          // q = h*16 + pt
            int h = q >> 4, pt = q & 15, l = pt >> 2;
            float logit = oan[256 + q];
            float m = logit;
            #pragma unroll
            for (int d = 1; d < 16; d <<= 1) m = fmaxf(m, __shfl_xor(m, d));
            float e = expf(logit - m);
            float ssum = e;
            #pragma unroll
            for (int d = 1; d < 16; d <<= 1) ssum += __shfl_xor(ssum, d);
            float aw = e / ssum;
            float2 off2 = *(const float2*)(oan + 2 * q);
            float2 ref2 = *(const float2*)(refp + (size_t)n * 8 + l * 2);
            int wl = sizes[l];
            float wf = (float)wl;
            float x = ref2.x * wf - 0.5f + off2.x;
            float y = ref2.y * wf - 0.5f + off2.y;
            float x0f = floorf(x), y0f = floorf(y);
            float fx = x - x0f, fy = y - y0f;
            int x0 = (int)x0f, y0 = (int)y0f;
            int x1 = x0 + 1, y1 = y0 + 1;
            float gx = 1.f - fx, gy = 1.f - fy;
            bool bx0 = (unsigned)x0 < (unsigned)wl, bx1 = (unsigned)x1 < (unsigned)wl;
            bool by0 = (unsigned)y0 < (unsigned)wl, by1 = (unsigned)y1 < (unsigned)wl;
            float w00 = (bx0 && by0) ? gx * gy * aw : 0.f;
            float w10 = (bx1 && by0) ? fx * gy * aw : 0.f;
            float w01 = (bx0 && by1) ? gx * fy * aw : 0.f;
            float w11 = (bx1 && by1) ? fx * fy * aw : 0.f;
            int x0c = min(max(x0, 0), wl - 1), x1c = min(max(x1, 0), wl - 1);
            int y0c = min(max(y0, 0), wl - 1), y1c = min(max(y1, 0), wl - 1);
            unsigned int base = (tokbase + (unsigned)starts[l]) * 256u + (unsigned)(h * 32);
            unsigned int r0 = base + (unsigned)(y0c * wl) * 256u;
            unsigned int r1 = base + (unsigned)(y1c * wl) * 256u;
            int idx = pt * 8 + (h ^ (pt & 7));
            s_ad[wv][idx] = make_uint4(r0 + (unsigned)x0c * 256u, r0 + (unsigned)x1c * 256u,
                                       r1 + (unsigned)x0c * 256u, r1 + (unsigned)x1c * 256u);
            s_wt[wv][idx] = make_float4(w00, w10, w01, w11);
        }
    }
    __syncthreads();
    if (n >= N_TOK) return;

    int h = lane >> 3, dq = lane & 7;
    unsigned int colo = (unsigned)(dq * 4);
    float a0 = 0.f, a1 = 0.f, a2 = 0.f, a3 = 0.f;

    #pragma unroll 8
    for (int pt = 0; pt < 16; ++pt) {
        int idx = pt * 8 + (h ^ (pt & 7));
        uint4 ad = s_ad[wv][idx];
        float4 wt = s_wt[wv][idx];
        uint2 u00 = *(const uint2*)(value + ad.x + colo);
        uint2 u10 = *(const uint2*)(value + ad.y + colo);
        uint2 u01 = *(const uint2*)(value + ad.z + colo);
        uint2 u11 = *(const uint2*)(value + ad.w + colo);
        a0 += wt.x * bflo(u00.x) + wt.y * bflo(u10.x) + wt.z * bflo(u01.x) + wt.w * bflo(u11.x);
        a1 += wt.x * bfhi(u00.x) + wt.y * bfhi(u10.x) + wt.z * bfhi(u01.x) + wt.w * bfhi(u11.x);
        a2 += wt.x * bflo(u00.y) + wt.y * bflo(u10.y) + wt.z * bflo(u01.y) + wt.w * bflo(u11.y);
        a3 += wt.x * bfhi(u00.y) + wt.y * bfhi(u10.y) + wt.z * bfhi(u01.y) + wt.w * bfhi(u11.y);
    }
    u16 o[4] = { f2bf(a0), f2bf(a1), f2bf(a2), f2bf(a3) };
    *(ushort4*)(out + (size_t)n * 256 + h * 32 + dq * 4) = *(ushort4*)o;
}

extern "C" void kernel_launch(void* const* d_in, const int* in_sizes, int n_in,
                              void* d_out, int out_size, void* d_ws, size_t ws_size,
                              hipStream_t stream) {
    const float* src    = (const float*)d_in[0];
    const float* pos    = (const float*)d_in[1];
    const float* refp   = (const float*)d_in[2];
    const float* w_value= (const float*)d_in[3];
    const float* b_value= (const float*)d_in[4];
    const float* w_off  = (const float*)d_in[5];
    const float* b_off  = (const float*)d_in[6];
    const float* w_attn = (const float*)d_in[7];
    const float* b_attn = (const float*)d_in[8];
    const float* w_out  = (const float*)d_in[9];
    const float* b_out  = (const float*)d_in[10];
    const float* ln1_g  = (const float*)d_in[11];
    const float* ln1_b  = (const float*)d_in[12];
    const float* w1     = (const float*)d_in[13];
    const float* b1     = (const float*)d_in[14];
    const float* w2     = (const float*)d_in[15];
    const float* b2     = (const float*)d_in[16];
    const float* ln2_g  = (const float*)d_in[17];
    const float* ln2_b  = (const float*)d_in[18];

    // ws layout (bytes):
    //   Vb  [0, 11523072) bf16 value ; OA [11523072, 46092288) f32  (both die after ms_sample)
    //   X   [0, 23046144) f32 ; Xb [23046144, 34569216) bf16   (overlays after death)
    //   Sb  [46092288, 57615360) bf16 ; Hb [57615360, 103707648) bf16
    //   weights [103707648, ...)
    char* w = (char*)d_ws;
    u16*   Vb = (u16*)w;
    float* OA = (float*)(w + 11523072);
    float* X  = (float*)w;
    u16*   Xb = (u16*)(w + 23046144);
    u16*   Sb = (u16*)(w + 46092288);
    u16*   Hb = (u16*)(w + 57615360);
    char*  WB = w + 103707648;
    u16* wv_t   = (u16*)WB;
    u16* woa_t  = wv_t + 65536;
    u16* wout_t = woa_t + 98304;
    u16* w1_t   = wout_t + 65536;
    u16* w2_t   = w1_t + 262144;
    float* boa  = (float*)(w2_t + 262144);
    float* out  = (float*)d_out;

    hipFuncSetAttribute((const void*)gemm_ln256,
                        hipFuncAttributeMaxDynamicSharedMemorySize, 131072);

    dim3 b256(256), b512(512);
    int MT = (N_TOK + 255) / 256;   // 88 super-tiles of 256 rows

    wprep<<<dim3(2946), b256, 0, stream>>>(w_value, w_off, w_attn, w_out, w1, w2,
                                           b_off, b_attn, wv_t, woa_t, wout_t, w1_t, w2_t, boa);
    // value(bf16) + [off|attn](f32): 5 panels x 88
    qv_panel<<<dim3(5 * MT), b512, 0, stream>>>(src, pos, wv_t, woa_t, b_value, boa, Vb, OA);
    // sampling (fused softmax) -> Sb bf16
    ms_sample<<<dim3((N_TOK + 3) / 4), b256, 0, stream>>>(Vb, OA, refp, Sb);
    // x = LN1(src + S @ w_out + b_out) -> X f32, Xb bf16
    gemm_ln256<<<dim3(MT), b512, 131072, stream>>>(Sb, wout_t, b_out, src,
                                                   ln1_g, ln1_b, X, Xb, 256, 1);
    // hidden = relu(x @ w1 + b1) -> Hb bf16 : 8 panels x 88
    panel_bf16<<<dim3(8 * MT), b512, 0, stream>>>(Xb, w1_t, b1, Hb, 1024, 8);
    // out = LN2(x + hidden @ w2 + b2) -> d_out f32 (K=1024, 4 chunks)
    gemm_ln256<<<dim3(MT), b512, 131072, stream>>>(Hb, w2_t, b2, X,
                                                   ln2_g, ln2_b, out, nullptr, 1024, 4);
}

// Round 9
// 224.057 us; speedup vs baseline: 1.2294x; 1.2294x over previous
//
#include <hip/hip_runtime.h>
#include <hip/hip_bf16.h>
#include <math.h>

#define N_TOK 22506
#define LEN   11253

typedef unsigned short u16;
typedef __attribute__((ext_vector_type(8))) short short8;
typedef __attribute__((ext_vector_type(4))) float f32x4;

#define GLOAD16(g, l) __builtin_amdgcn_global_load_lds( \
    (const __attribute__((address_space(1))) void*)(g), \
    (__attribute__((address_space(3))) void*)(l), 16, 0, 0)

static __device__ __forceinline__ u16 f2bf(float f) {
    unsigned int u = __builtin_bit_cast(unsigned int, f);
    u = (u + 0x7fffu + ((u >> 16) & 1u)) >> 16;
    return (u16)u;
}
static __device__ __forceinline__ float bflo(unsigned int u) {
    return __builtin_bit_cast(float, u << 16);
}
static __device__ __forceinline__ float bfhi(unsigned int u) {
    return __builtin_bit_cast(float, u & 0xffff0000u);
}

// bijective XCD-chunked swizzle (m204)
static __device__ __forceinline__ int xcd_swz(int id, int nwg) {
    int q = nwg >> 3, r = nwg & 7;
    int xcd = id & 7, rank = id >> 3;
    return (xcd < r ? xcd * (q + 1) : r * (q + 1) + (xcd - r) * q) + rank;
}

// ---- weight transposes (f32 -> bf16, [K][N] -> [N][K]) + bias concat ----
__global__ __launch_bounds__(256) void wprep(
    const float* __restrict__ w_value, const float* __restrict__ w_off,
    const float* __restrict__ w_attn, const float* __restrict__ w_out,
    const float* __restrict__ w1, const float* __restrict__ w2,
    const float* __restrict__ b_off, const float* __restrict__ b_attn,
    u16* __restrict__ wv_t, u16* __restrict__ woa_t, u16* __restrict__ wout_t,
    u16* __restrict__ w1_t, u16* __restrict__ w2_t, float* __restrict__ boa)
{
    int i = blockIdx.x * 256 + threadIdx.x;
    if (i < 65536) {
        wv_t[(i & 255) * 256 + (i >> 8)] = f2bf(w_value[i]);
    } else if (i < 131072) {
        int j = i - 65536;
        woa_t[(j & 255) * 256 + (j >> 8)] = f2bf(w_off[j]);
    } else if (i < 163840) {
        int j = i - 131072;
        woa_t[65536 + (j & 127) * 256 + (j >> 7)] = f2bf(w_attn[j]);
    } else if (i < 229376) {
        int j = i - 163840;
        wout_t[(j & 255) * 256 + (j >> 8)] = f2bf(w_out[j]);
    } else if (i < 491520) {
        int j = i - 229376;
        w1_t[(j & 1023) * 256 + (j >> 10)] = f2bf(w1[j]);
    } else if (i < 753664) {
        int j = i - 491520;
        w2_t[(j & 255) * 1024 + (j >> 8)] = f2bf(w2[j]);
    } else if (i < 754048) {
        int j = i - 753664;
        boa[j] = (j < 256) ? b_off[j] : b_attn[j - 256];
    }
}

// ---- srcb = bf16(src), qb = bf16(src+pos) ----
__global__ __launch_bounds__(256) void cvt_src(const float* __restrict__ src,
                                               const float* __restrict__ pos,
                                               u16* __restrict__ srcb, u16* __restrict__ qb,
                                               int n4)
{
    int i = blockIdx.x * 256 + threadIdx.x;
    if (i >= n4) return;
    float4 s = ((const float4*)src)[i];
    float4 p = ((const float4*)pos)[i];
    u16 sb[4] = { f2bf(s.x), f2bf(s.y), f2bf(s.z), f2bf(s.w) };
    u16 q4[4] = { f2bf(s.x + p.x), f2bf(s.y + p.y), f2bf(s.z + p.z), f2bf(s.w + p.w) };
    *(ushort4*)(srcb + (size_t)i * 4) = *(ushort4*)sb;
    *(ushort4*)(qb + (size_t)i * 4) = *(ushort4*)q4;
}

// ============ pipelined bf16 MFMA GEMM: 128x128 tile, BK=32, 3-deep ============
// 256 thr = 4 waves (2x2). Counted vmcnt; 2 barriers per K-step (read-safety).
__global__ __launch_bounds__(256) void gemm2(
    const u16* __restrict__ A, const u16* __restrict__ Bt,
    const float* __restrict__ bias, float* __restrict__ Cf, u16* __restrict__ Cb,
    int M, int Nc, int K, int relu)
{
    __shared__ u16 As[3 * 4096];   // 3 x 8KB: [r 0..127][k 0..31] slot-swizzled
    __shared__ u16 Bs[3 * 4096];
    int tid = threadIdx.x;
    int lane = tid & 63, wid = tid >> 6;
    int wr = wid >> 1, wc = wid & 1;

    int nwg = gridDim.x * gridDim.y;
    int sid = xcd_swz(blockIdx.y * gridDim.x + blockIdx.x, nwg);
    int bm = (sid / gridDim.x) * 128, bn = (sid % gridDim.x) * 128;

    f32x4 acc[4][4] = {};
    int srcslot = ((lane & 3) ^ ((lane >> 2) & 3) ^ ((lane >> 4) & 3)) << 3;
    int lrow = lane >> 2;   // row-within-16-chunk

    auto stage = [&](int t) {
        int k0 = t * 32, sb = t % 3;
        #pragma unroll
        for (int c = 0; c < 2; ++c) {
            int rr = wid * 32 + c * 16 + lrow;
            int ra = bm + rr; ra = ra < M ? ra : M - 1;
            GLOAD16(A + (size_t)ra * K + k0 + srcslot,
                    (char*)As + sb * 8192 + wid * 2048 + c * 1024);
            GLOAD16(Bt + (size_t)(bn + rr) * K + k0 + srcslot,
                    (char*)Bs + sb * 8192 + wid * 2048 + c * 1024);
        }
    };

    int KT = K >> 5;
    stage(0); stage(1); stage(2);

    int rlo = lane & 15, khalf = lane >> 4;
    int fsl = ((khalf ^ (rlo & 3) ^ ((rlo >> 2) & 3)) << 3);

    for (int t = 0; t < KT; ++t) {
        if (t + 2 < KT)      asm volatile("s_waitcnt vmcnt(8)" ::: "memory");
        else if (t + 1 < KT) asm volatile("s_waitcnt vmcnt(4)" ::: "memory");
        else                 asm volatile("s_waitcnt vmcnt(0)" ::: "memory");
        __builtin_amdgcn_s_barrier();              // buffer t%3 ready
        __builtin_amdgcn_sched_barrier(0);

        const u16* a_lds = As + (t % 3) * 4096;
        const u16* b_lds = Bs + (t % 3) * 4096;
        short8 af[4], bf_[4];
        #pragma unroll
        for (int mi = 0; mi < 4; ++mi)
            af[mi] = *(const short8*)(a_lds + (wr * 64 + mi * 16 + rlo) * 32 + fsl);
        #pragma unroll
        for (int ni = 0; ni < 4; ++ni)
            bf_[ni] = *(const short8*)(b_lds + (wc * 64 + ni * 16 + rlo) * 32 + fsl);

        __builtin_amdgcn_s_setprio(1);
        #pragma unroll
        for (int mi = 0; mi < 4; ++mi)
            #pragma unroll
            for (int ni = 0; ni < 4; ++ni)
                acc[mi][ni] = __builtin_amdgcn_mfma_f32_16x16x32_bf16(
                    af[mi], bf_[ni], acc[mi][ni], 0, 0, 0);
        __builtin_amdgcn_s_setprio(0);

        __builtin_amdgcn_sched_barrier(0);
        asm volatile("s_waitcnt lgkmcnt(0)" ::: "memory");
        __builtin_amdgcn_s_barrier();              // all waves done reading buf t%3
        if (t + 3 < KT) stage(t + 3);              // safe overwrite now
    }

    int col_l = lane & 15, rgrp = lane >> 4;
    #pragma unroll
    for (int mi = 0; mi < 4; ++mi) {
        #pragma unroll
        for (int j = 0; j < 4; ++j) {
            int row = bm + wr * 64 + mi * 16 + rgrp * 4 + j;
            if (row >= M) continue;
            #pragma unroll
            for (int ni = 0; ni < 4; ++ni) {
                int col = bn + wc * 64 + ni * 16 + col_l;
                float v = acc[mi][ni][j];
                if (bias) v += bias[col];
                if (relu) v = fmaxf(v, 0.f);
                if (Cf) Cf[(size_t)row * Nc + col] = v;
                if (Cb) Cb[(size_t)row * Nc + col] = f2bf(v);
            }
        }
    }
}

// ============ pipelined Nc=256 GEMM + residual + LayerNorm, BK=32, 3-deep ============
// 256 thr = 4 waves along cols; 64-row tile x full 256 cols.
__global__ __launch_bounds__(256) void gemm_ln(
    const u16* __restrict__ A, const u16* __restrict__ Bt,
    const float* __restrict__ bias, const float* __restrict__ res,
    const float* __restrict__ g, const float* __restrict__ beta,
    float* __restrict__ outf, u16* __restrict__ outb,
    int M, int K)
{
    __shared__ u16 As[3 * 2048];   // 3 x 4KB: [r 0..63][k 0..31]
    __shared__ u16 Bs[3 * 8192];   // 3 x 16KB: [c 0..255][k 0..31]
    int tid = threadIdx.x;
    int lane = tid & 63, wc = tid >> 6;
    int bm = blockIdx.x * 64;
    f32x4 acc[4][4] = {};
    int srcslot = ((lane & 3) ^ ((lane >> 2) & 3) ^ ((lane >> 4) & 3)) << 3;
    int lrow = lane >> 2;

    auto stage = [&](int t) {
        int k0 = t * 32, sb = t % 3;
        int ra = bm + wc * 16 + lrow; ra = ra < M ? ra : M - 1;
        GLOAD16(A + (size_t)ra * K + k0 + srcslot,
                (char*)As + sb * 4096 + wc * 1024);
        #pragma unroll
        for (int i = 0; i < 4; ++i) {
            int cc = i * 64 + wc * 16 + lrow;
            GLOAD16(Bt + (size_t)cc * K + k0 + srcslot,
                    (char*)Bs + sb * 16384 + i * 4096 + wc * 1024);
        }
    };

    int KT = K >> 5;
    stage(0); stage(1); stage(2);

    int rlo = lane & 15, khalf = lane >> 4;
    int fsl = ((khalf ^ (rlo & 3) ^ ((rlo >> 2) & 3)) << 3);

    for (int t = 0; t < KT; ++t) {
        if (t + 2 < KT)      asm volatile("s_waitcnt vmcnt(10)" ::: "memory");
        else if (t + 1 < KT) asm volatile("s_waitcnt vmcnt(5)" ::: "memory");
        else                 asm volatile("s_waitcnt vmcnt(0)" ::: "memory");
        __builtin_amdgcn_s_barrier();              // buffer t%3 ready
        __builtin_amdgcn_sched_barrier(0);

        const u16* a_lds = As + (t % 3) * 2048;
        const u16* b_lds = Bs + (t % 3) * 8192;
        short8 af[4], bf_[4];
        #pragma unroll
        for (int mi = 0; mi < 4; ++mi)
            af[mi] = *(const short8*)(a_lds + (mi * 16 + rlo) * 32 + fsl);
        #pragma unroll
        for (int ni = 0; ni < 4; ++ni)
            bf_[ni] = *(const short8*)(b_lds + (wc * 64 + ni * 16 + rlo) * 32 + fsl);

        __builtin_amdgcn_s_setprio(1);
        #pragma unroll
        for (int mi = 0; mi < 4; ++mi)
            #pragma unroll
            for (int ni = 0; ni < 4; ++ni)
                acc[mi][ni] = __builtin_amdgcn_mfma_f32_16x16x32_bf16(
                    af[mi], bf_[ni], acc[mi][ni], 0, 0, 0);
        __builtin_amdgcn_s_setprio(0);

        __builtin_amdgcn_sched_barrier(0);
        asm volatile("s_waitcnt lgkmcnt(0)" ::: "memory");
        __builtin_amdgcn_s_barrier();              // all waves done reading buf t%3
        if (t + 3 < KT) stage(t + 3);
    }
    __syncthreads();

    // epilogue: v = acc + bias + res; LayerNorm over the 256-col row
    float* red = (float*)As;
    int col_l = lane & 15, rgrp = lane >> 4;
    int colc[4]; float bias_c[4], g_c[4], be_c[4];
    #pragma unroll
    for (int ni = 0; ni < 4; ++ni) {
        colc[ni] = wc * 64 + ni * 16 + col_l;
        bias_c[ni] = bias[colc[ni]];
        g_c[ni]  = g[colc[ni]];
        be_c[ni] = beta[colc[ni]];
    }
    #pragma unroll
    for (int mi = 0; mi < 4; ++mi) {
        #pragma unroll
        for (int j = 0; j < 4; ++j) {
            int rl = mi * 16 + rgrp * 4 + j;
            int row = bm + rl;
            float s = 0.f, s2 = 0.f;
            if (row < M) {
                #pragma unroll
                for (int ni = 0; ni < 4; ++ni) {
                    float v = acc[mi][ni][j] + bias_c[ni] + res[(size_t)row * 256 + colc[ni]];
                    acc[mi][ni][j] = v;
                    s += v; s2 += v * v;
                }
            }
            #pragma unroll
            for (int d = 1; d < 16; d <<= 1) { s += __shfl_xor(s, d); s2 += __shfl_xor(s2, d); }
            if (col_l == 0) { red[wc * 64 + rl] = s; red[256 + wc * 64 + rl] = s2; }
        }
    }
    __syncthreads();
    if (tid < 64) {
        float s  = red[tid] + red[64 + tid] + red[128 + tid] + red[192 + tid];
        float s2 = red[256 + tid] + red[320 + tid] + red[384 + tid] + red[448 + tid];
        float mean = s * (1.f / 256.f);
        float var = s2 * (1.f / 256.f) - mean * mean;
        red[512 + tid] = mean;
        red[576 + tid] = rsqrtf(var + 1e-5f);
    }
    __syncthreads();
    #pragma unroll
    for (int mi = 0; mi < 4; ++mi) {
        #pragma unroll
        for (int j = 0; j < 4; ++j) {
            int rl = mi * 16 + rgrp * 4 + j;
            int row = bm + rl;
            if (row >= M) continue;
            float mean = red[512 + rl], rs = red[576 + rl];
            #pragma unroll
            for (int ni = 0; ni < 4; ++ni) {
                float o = g_c[ni] * (acc[mi][ni][j] - mean) * rs + be_c[ni];
                outf[(size_t)row * 256 + colc[ni]] = o;
                if (outb) outb[(size_t)row * 256 + colc[ni]] = f2bf(o);
            }
        }
    }
}

// ---- deformable sampling, phase-split, bf16 value, XOR-permuted LDS ----
__global__ __launch_bounds__(256) void ms_sample(
    const u16* __restrict__ value, const float* __restrict__ oa,
    const float* __restrict__ refp, u16* __restrict__ out)
{
    const int starts[4] = {0, 8464, 10580, 11109};
    const int sizes[4]  = {92, 46, 23, 12};
    int t = threadIdx.x;
    int wv = t >> 6, lane = t & 63;
    int n = blockIdx.x * 4 + wv;

    __shared__ uint4  s_ad[4][128];
    __shared__ float4 s_wt[4][128];

    if (n < N_TOK) {
        const float* oan = oa + (size_t)n * 384;
        unsigned int tokbase = (n >= LEN) ? (unsigned)LEN : 0u;
        #pragma unroll
        for (int rep = 0; rep < 2; ++rep) {
            int q = rep * 64 + lane;          // q = h*16 + pt
            int h = q >> 4, pt = q & 15, l = pt >> 2;
            float logit = oan[256 + q];
            float m = logit;
            #pragma unroll
            for (int d = 1; d < 16; d <<= 1) m = fmaxf(m, __shfl_xor(m, d));
            float e = expf(logit - m);
            float ssum = e;
            #pragma unroll
            for (int d = 1; d < 16; d <<= 1) ssum += __shfl_xor(ssum, d);
            float aw = e / ssum;
            float2 off2 = *(const float2*)(oan + 2 * q);
            float2 ref2 = *(const float2*)(refp + (size_t)n * 8 + l * 2);
            int wl = sizes[l];
            float wf = (float)wl;
            float x = ref2.x * wf - 0.5f + off2.x;
            float y = ref2.y * wf - 0.5f + off2.y;
            float x0f = floorf(x), y0f = floorf(y);
            float fx = x - x0f, fy = y - y0f;
            int x0 = (int)x0f, y0 = (int)y0f;
            int x1 = x0 + 1, y1 = y0 + 1;
            float gx = 1.f - fx, gy = 1.f - fy;
            bool bx0 = (unsigned)x0 < (unsigned)wl, bx1 = (unsigned)x1 < (unsigned)wl;
            bool by0 = (unsigned)y0 < (unsigned)wl, by1 = (unsigned)y1 < (unsigned)wl;
            float w00 = (bx0 && by0) ? gx * gy * aw : 0.f;
            float w10 = (bx1 && by0) ? fx * gy * aw : 0.f;
            float w01 = (bx0 && by1) ? gx * fy * aw : 0.f;
            float w11 = (bx1 && by1) ? fx * fy * aw : 0.f;
            int x0c = min(max(x0, 0), wl - 1), x1c = min(max(x1, 0), wl - 1);
            int y0c = min(max(y0, 0), wl - 1), y1c = min(max(y1, 0), wl - 1);
            unsigned int base = (tokbase + (unsigned)starts[l]) * 256u + (unsigned)(h * 32);
            unsigned int r0 = base + (unsigned)(y0c * wl) * 256u;
            unsigned int r1 = base + (unsigned)(y1c * wl) * 256u;
            int idx = pt * 8 + (h ^ (pt & 7));
            s_ad[wv][idx] = make_uint4(r0 + (unsigned)x0c * 256u, r0 + (unsigned)x1c * 256u,
                                       r1 + (unsigned)x0c * 256u, r1 + (unsigned)x1c * 256u);
            s_wt[wv][idx] = make_float4(w00, w10, w01, w11);
        }
    }
    __syncthreads();
    if (n >= N_TOK) return;

    int h = lane >> 3, dq = lane & 7;
    unsigned int colo = (unsigned)(dq * 4);
    float a0 = 0.f, a1 = 0.f, a2 = 0.f, a3 = 0.f;

    #pragma unroll 8
    for (int pt = 0; pt < 16; ++pt) {
        int idx = pt * 8 + (h ^ (pt & 7));
        uint4 ad = s_ad[wv][idx];
        float4 wt = s_wt[wv][idx];
        uint2 u00 = *(const uint2*)(value + ad.x + colo);
        uint2 u10 = *(const uint2*)(value + ad.y + colo);
        uint2 u01 = *(const uint2*)(value + ad.z + colo);
        uint2 u11 = *(const uint2*)(value + ad.w + colo);
        a0 += wt.x * bflo(u00.x) + wt.y * bflo(u10.x) + wt.z * bflo(u01.x) + wt.w * bflo(u11.x);
        a1 += wt.x * bfhi(u00.x) + wt.y * bfhi(u10.x) + wt.z * bfhi(u01.x) + wt.w * bfhi(u11.x);
        a2 += wt.x * bflo(u00.y) + wt.y * bflo(u10.y) + wt.z * bflo(u01.y) + wt.w * bflo(u11.y);
        a3 += wt.x * bfhi(u00.y) + wt.y * bfhi(u10.y) + wt.z * bfhi(u01.y) + wt.w * bfhi(u11.y);
    }
    u16 o[4] = { f2bf(a0), f2bf(a1), f2bf(a2), f2bf(a3) };
    *(ushort4*)(out + (size_t)n * 256 + h * 32 + dq * 4) = *(ushort4*)o;
}

extern "C" void kernel_launch(void* const* d_in, const int* in_sizes, int n_in,
                              void* d_out, int out_size, void* d_ws, size_t ws_size,
                              hipStream_t stream) {
    const float* src    = (const float*)d_in[0];
    const float* pos    = (const float*)d_in[1];
    const float* refp   = (const float*)d_in[2];
    const float* w_value= (const float*)d_in[3];
    const float* b_value= (const float*)d_in[4];
    const float* w_off  = (const float*)d_in[5];
    const float* b_off  = (const float*)d_in[6];
    const float* w_attn = (const float*)d_in[7];
    const float* b_attn = (const float*)d_in[8];
    const float* w_out  = (const float*)d_in[9];
    const float* b_out  = (const float*)d_in[10];
    const float* ln1_g  = (const float*)d_in[11];
    const float* ln1_b  = (const float*)d_in[12];
    const float* w1     = (const float*)d_in[13];
    const float* b1     = (const float*)d_in[14];
    const float* w2     = (const float*)d_in[15];
    const float* b2     = (const float*)d_in[16];
    const float* ln2_g  = (const float*)d_in[17];
    const float* ln2_b  = (const float*)d_in[18];

    // ws layout (bytes), liveness-packed (~93.7 MB total):
    //   srcb [0, 11523072)         bf16; dead after value-GEMM; then Sb (sample out)
    //   Vb   [11523072, 23046144)  bf16; dead after sample
    //   qb   [23046144, 34569216)  bf16; dead after oa-GEMM
    //   X    [11523072, 34569216)  f32  LN1 out (overlays Vb+qb, written phase4)
    //   OA   [34569216, 69138432)  f32; dead after sample
    //   Xb   [34569216, 46092288)  bf16 LN1 out (overlays OA head)
    //   Hb   [46092288, 92184576)  bf16 FFN hidden (overlays OA tail + fresh)
    //   weights [92184576, ...)
    char* w = (char*)d_ws;
    u16*   srcb = (u16*)w;
    u16*   Sb   = srcb;
    u16*   Vb   = (u16*)(w + 11523072);
    u16*   qb   = (u16*)(w + 23046144);
    float* X    = (float*)(w + 11523072);
    float* OA   = (float*)(w + 34569216);
    u16*   Xb   = (u16*)(w + 34569216);
    u16*   Hb   = (u16*)(w + 46092288);
    char*  WB   = w + 92184576;
    u16* wv_t   = (u16*)WB;
    u16* woa_t  = wv_t + 65536;
    u16* wout_t = woa_t + 98304;
    u16* w1_t   = wout_t + 65536;
    u16* w2_t   = w1_t + 262144;
    float* boa  = (float*)(w2_t + 262144);
    float* out  = (float*)d_out;

    const size_t NV = (size_t)N_TOK * 256;
    dim3 b256(256);
    int MB = (N_TOK + 127) / 128;   // 176

    wprep<<<dim3(2946), b256, 0, stream>>>(w_value, w_off, w_attn, w_out, w1, w2,
                                           b_off, b_attn, wv_t, woa_t, wout_t, w1_t, w2_t, boa);
    cvt_src<<<dim3((int)(NV / 4 + 255) / 256), b256, 0, stream>>>(src, pos, srcb, qb, (int)(NV / 4));
    // value = srcb @ wv + b -> Vb bf16
    gemm2<<<dim3(2, MB), b256, 0, stream>>>(srcb, wv_t, b_value, nullptr, Vb, N_TOK, 256, 256, 0);
    // [off|attn] = qb @ woa + b -> OA f32
    gemm2<<<dim3(3, MB), b256, 0, stream>>>(qb, woa_t, boa, OA, nullptr, N_TOK, 384, 256, 0);
    // sampling (fused softmax) -> Sb bf16 (reuses srcb)
    ms_sample<<<dim3((N_TOK + 3) / 4), b256, 0, stream>>>(Vb, OA, refp, Sb);
    // x = LN1(src + Sb @ w_out + b_out) -> X f32, Xb bf16
    gemm_ln<<<dim3((N_TOK + 63) / 64), b256, 0, stream>>>(Sb, wout_t, b_out, src,
                                                          ln1_g, ln1_b, X, Xb, N_TOK, 256);
    // hidden = relu(Xb @ w1 + b1) -> Hb bf16
    gemm2<<<dim3(8, MB), b256, 0, stream>>>(Xb, w1_t, b1, nullptr, Hb, N_TOK, 1024, 256, 1);
    // out = LN2(X + Hb @ w2 + b2) -> d_out f32
    gemm_ln<<<dim3((N_TOK + 63) / 64), b256, 0, stream>>>(Hb, w2_t, b2, X,
                                                          ln2_g, ln2_b, out, nullptr, N_TOK, 1024);
}

// Round 10
// 209.496 us; speedup vs baseline: 1.3148x; 1.0695x over previous
//
#include <hip/hip_runtime.h>
#include <hip/hip_bf16.h>
#include <math.h>

#define N_TOK 22506
#define LEN   11253

typedef unsigned short u16;
typedef __attribute__((ext_vector_type(8))) short short8;
typedef __attribute__((ext_vector_type(4))) float f32x4;
typedef __attribute__((ext_vector_type(2))) float f32x2;
typedef __attribute__((ext_vector_type(2))) unsigned int u32x2;

#define GLOAD16(g, l) __builtin_amdgcn_global_load_lds( \
    (const __attribute__((address_space(1))) void*)(g), \
    (__attribute__((address_space(3))) void*)(l), 16, 0, 0)

static __device__ __forceinline__ u16 f2bf(float f) {
    unsigned int u = __builtin_bit_cast(unsigned int, f);
    u = (u + 0x7fffu + ((u >> 16) & 1u)) >> 16;
    return (u16)u;
}
// unpack 2 bf16 (one dword) -> f32 pair
static __device__ __forceinline__ f32x2 bf2x2(unsigned int a) {
    u32x2 t = { a << 16, a & 0xffff0000u };
    return __builtin_bit_cast(f32x2, t);
}

// bijective XCD-chunked swizzle (m204)
static __device__ __forceinline__ int xcd_swz(int id, int nwg) {
    int q = nwg >> 3, r = nwg & 7;
    int xcd = id & 7, rank = id >> 3;
    return (xcd < r ? xcd * (q + 1) : r * (q + 1) + (xcd - r) * q) + rank;
}

// ---- weight transposes + bias concat + src/q bf16 conversion, one dispatch ----
__global__ __launch_bounds__(256) void wprep(
    const float* __restrict__ w_value, const float* __restrict__ w_off,
    const float* __restrict__ w_attn, const float* __restrict__ w_out,
    const float* __restrict__ w1, const float* __restrict__ w2,
    const float* __restrict__ b_off, const float* __restrict__ b_attn,
    const float* __restrict__ src, const float* __restrict__ pos,
    u16* __restrict__ wv_t, u16* __restrict__ woa_t, u16* __restrict__ wout_t,
    u16* __restrict__ w1_t, u16* __restrict__ w2_t, float* __restrict__ boa,
    u16* __restrict__ srcb, u16* __restrict__ qb)
{
    int i = blockIdx.x * 256 + threadIdx.x;
    if (i < 65536) {
        wv_t[(i & 255) * 256 + (i >> 8)] = f2bf(w_value[i]);
    } else if (i < 131072) {
        int j = i - 65536;
        woa_t[(j & 255) * 256 + (j >> 8)] = f2bf(w_off[j]);
    } else if (i < 163840) {
        int j = i - 131072;
        woa_t[65536 + (j & 127) * 256 + (j >> 7)] = f2bf(w_attn[j]);
    } else if (i < 229376) {
        int j = i - 163840;
        wout_t[(j & 255) * 256 + (j >> 8)] = f2bf(w_out[j]);
    } else if (i < 491520) {
        int j = i - 229376;
        w1_t[(j & 1023) * 256 + (j >> 10)] = f2bf(w1[j]);
    } else if (i < 753664) {
        int j = i - 491520;
        w2_t[(j & 255) * 1024 + (j >> 8)] = f2bf(w2[j]);
    } else if (i < 754048) {
        int j = i - 753664;
        boa[j] = (j < 256) ? b_off[j] : b_attn[j - 256];
    } else if (i < 754048 + 1440384) {
        int j = i - 754048;                 // float4 index over N_TOK*256
        float4 s = ((const float4*)src)[j];
        float4 p = ((const float4*)pos)[j];
        u16 sb[4] = { f2bf(s.x), f2bf(s.y), f2bf(s.z), f2bf(s.w) };
        u16 q4[4] = { f2bf(s.x + p.x), f2bf(s.y + p.y), f2bf(s.z + p.z), f2bf(s.w + p.w) };
        *(ushort4*)(srcb + (size_t)j * 4) = *(ushort4*)sb;
        *(ushort4*)(qb + (size_t)j * 4) = *(ushort4*)q4;
    }
}

// ============ fused value + off/attn GEMM: 128x128 tile, BK=32, 3-deep ============
// sid%5: p<2 -> value job (A=srcb, B=wv, out Vb bf16); else off|attn (A=qb, B=woa, out OA f32).
__global__ __launch_bounds__(256) void gemm5(
    const u16* __restrict__ srcb, const u16* __restrict__ qb,
    const u16* __restrict__ wv_t, const u16* __restrict__ woa_t,
    const float* __restrict__ b_value, const float* __restrict__ boa,
    u16* __restrict__ Vb, float* __restrict__ OA)
{
    __shared__ u16 As[3 * 4096];
    __shared__ u16 Bs[3 * 4096];
    int tid = threadIdx.x;
    int lane = tid & 63, wid = tid >> 6;
    int wr = wid >> 1, wc = wid & 1;

    int sid = xcd_swz(blockIdx.x, gridDim.x);
    int p = sid % 5, bm = (sid / 5) * 128;
    int job = p < 2 ? 0 : 1;
    int bn = job ? (p - 2) * 128 : p * 128;
    const u16* A  = job ? qb : srcb;
    const u16* Bt = job ? woa_t : wv_t;

    f32x4 acc[4][4] = {};
    int srcslot = ((lane & 3) ^ ((lane >> 2) & 3) ^ ((lane >> 4) & 3)) << 3;
    int lrow = lane >> 2;

    auto stage = [&](int t) {
        int k0 = t * 32, sb = t % 3;
        #pragma unroll
        for (int c = 0; c < 2; ++c) {
            int rr = wid * 32 + c * 16 + lrow;
            int ra = bm + rr; ra = ra < N_TOK ? ra : N_TOK - 1;
            GLOAD16(A + (size_t)ra * 256 + k0 + srcslot,
                    (char*)As + sb * 8192 + wid * 2048 + c * 1024);
            GLOAD16(Bt + (size_t)(bn + rr) * 256 + k0 + srcslot,
                    (char*)Bs + sb * 8192 + wid * 2048 + c * 1024);
        }
    };

    stage(0); stage(1); stage(2);

    int rlo = lane & 15, khalf = lane >> 4;
    int fsl = ((khalf ^ (rlo & 3) ^ ((rlo >> 2) & 3)) << 3);

    for (int t = 0; t < 8; ++t) {
        if (t + 2 < 8)      asm volatile("s_waitcnt vmcnt(8)" ::: "memory");
        else if (t + 1 < 8) asm volatile("s_waitcnt vmcnt(4)" ::: "memory");
        else                asm volatile("s_waitcnt vmcnt(0)" ::: "memory");
        __builtin_amdgcn_s_barrier();
        __builtin_amdgcn_sched_barrier(0);

        const u16* a_lds = As + (t % 3) * 4096;
        const u16* b_lds = Bs + (t % 3) * 4096;
        short8 af[4], bf_[4];
        #pragma unroll
        for (int mi = 0; mi < 4; ++mi)
            af[mi] = *(const short8*)(a_lds + (wr * 64 + mi * 16 + rlo) * 32 + fsl);
        #pragma unroll
        for (int ni = 0; ni < 4; ++ni)
            bf_[ni] = *(const short8*)(b_lds + (wc * 64 + ni * 16 + rlo) * 32 + fsl);

        __builtin_amdgcn_s_setprio(1);
        #pragma unroll
        for (int mi = 0; mi < 4; ++mi)
            #pragma unroll
            for (int ni = 0; ni < 4; ++ni)
                acc[mi][ni] = __builtin_amdgcn_mfma_f32_16x16x32_bf16(
                    af[mi], bf_[ni], acc[mi][ni], 0, 0, 0);
        __builtin_amdgcn_s_setprio(0);

        __builtin_amdgcn_sched_barrier(0);
        asm volatile("s_waitcnt lgkmcnt(0)" ::: "memory");
        __builtin_amdgcn_s_barrier();
        if (t + 3 < 8) stage(t + 3);
    }

    int col_l = lane & 15, rgrp = lane >> 4;
    #pragma unroll
    for (int mi = 0; mi < 4; ++mi) {
        #pragma unroll
        for (int j = 0; j < 4; ++j) {
            int row = bm + wr * 64 + mi * 16 + rgrp * 4 + j;
            if (row >= N_TOK) continue;
            #pragma unroll
            for (int ni = 0; ni < 4; ++ni) {
                int col = bn + wc * 64 + ni * 16 + col_l;
                if (job) OA[(size_t)row * 384 + col] = acc[mi][ni][j] + boa[col];
                else     Vb[(size_t)row * 256 + col] = f2bf(acc[mi][ni][j] + b_value[col]);
            }
        }
    }
}

// ============ pipelined bf16 MFMA GEMM: 128x128 tile, BK=32, 3-deep (FFN1) ============
__global__ __launch_bounds__(256) void gemm2(
    const u16* __restrict__ A, const u16* __restrict__ Bt,
    const float* __restrict__ bias, float* __restrict__ Cf, u16* __restrict__ Cb,
    int M, int Nc, int K, int relu)
{
    __shared__ u16 As[3 * 4096];
    __shared__ u16 Bs[3 * 4096];
    int tid = threadIdx.x;
    int lane = tid & 63, wid = tid >> 6;
    int wr = wid >> 1, wc = wid & 1;

    int nwg = gridDim.x * gridDim.y;
    int sid = xcd_swz(blockIdx.y * gridDim.x + blockIdx.x, nwg);
    int bm = (sid / gridDim.x) * 128, bn = (sid % gridDim.x) * 128;

    f32x4 acc[4][4] = {};
    int srcslot = ((lane & 3) ^ ((lane >> 2) & 3) ^ ((lane >> 4) & 3)) << 3;
    int lrow = lane >> 2;

    auto stage = [&](int t) {
        int k0 = t * 32, sb = t % 3;
        #pragma unroll
        for (int c = 0; c < 2; ++c) {
            int rr = wid * 32 + c * 16 + lrow;
            int ra = bm + rr; ra = ra < M ? ra : M - 1;
            GLOAD16(A + (size_t)ra * K + k0 + srcslot,
                    (char*)As + sb * 8192 + wid * 2048 + c * 1024);
            GLOAD16(Bt + (size_t)(bn + rr) * K + k0 + srcslot,
                    (char*)Bs + sb * 8192 + wid * 2048 + c * 1024);
        }
    };

    int KT = K >> 5;
    stage(0); stage(1); stage(2);

    int rlo = lane & 15, khalf = lane >> 4;
    int fsl = ((khalf ^ (rlo & 3) ^ ((rlo >> 2) & 3)) << 3);

    for (int t = 0; t < KT; ++t) {
        if (t + 2 < KT)      asm volatile("s_waitcnt vmcnt(8)" ::: "memory");
        else if (t + 1 < KT) asm volatile("s_waitcnt vmcnt(4)" ::: "memory");
        else                 asm volatile("s_waitcnt vmcnt(0)" ::: "memory");
        __builtin_amdgcn_s_barrier();
        __builtin_amdgcn_sched_barrier(0);

        const u16* a_lds = As + (t % 3) * 4096;
        const u16* b_lds = Bs + (t % 3) * 4096;
        short8 af[4], bf_[4];
        #pragma unroll
        for (int mi = 0; mi < 4; ++mi)
            af[mi] = *(const short8*)(a_lds + (wr * 64 + mi * 16 + rlo) * 32 + fsl);
        #pragma unroll
        for (int ni = 0; ni < 4; ++ni)
            bf_[ni] = *(const short8*)(b_lds + (wc * 64 + ni * 16 + rlo) * 32 + fsl);

        __builtin_amdgcn_s_setprio(1);
        #pragma unroll
        for (int mi = 0; mi < 4; ++mi)
            #pragma unroll
            for (int ni = 0; ni < 4; ++ni)
                acc[mi][ni] = __builtin_amdgcn_mfma_f32_16x16x32_bf16(
                    af[mi], bf_[ni], acc[mi][ni], 0, 0, 0);
        __builtin_amdgcn_s_setprio(0);

        __builtin_amdgcn_sched_barrier(0);
        asm volatile("s_waitcnt lgkmcnt(0)" ::: "memory");
        __builtin_amdgcn_s_barrier();
        if (t + 3 < KT) stage(t + 3);
    }

    int col_l = lane & 15, rgrp = lane >> 4;
    #pragma unroll
    for (int mi = 0; mi < 4; ++mi) {
        #pragma unroll
        for (int j = 0; j < 4; ++j) {
            int row = bm + wr * 64 + mi * 16 + rgrp * 4 + j;
            if (row >= M) continue;
            #pragma unroll
            for (int ni = 0; ni < 4; ++ni) {
                int col = bn + wc * 64 + ni * 16 + col_l;
                float v = acc[mi][ni][j];
                if (bias) v += bias[col];
                if (relu) v = fmaxf(v, 0.f);
                if (Cf) Cf[(size_t)row * Nc + col] = v;
                if (Cb) Cb[(size_t)row * Nc + col] = f2bf(v);
            }
        }
    }
}

// ============ pipelined Nc=256 GEMM + residual + LayerNorm, BK=32, 3-deep ============
__global__ __launch_bounds__(256) void gemm_ln(
    const u16* __restrict__ A, const u16* __restrict__ Bt,
    const float* __restrict__ bias, const float* __restrict__ res,
    const float* __restrict__ g, const float* __restrict__ beta,
    float* __restrict__ outf, u16* __restrict__ outb,
    int M, int K)
{
    __shared__ u16 As[3 * 2048];
    __shared__ u16 Bs[3 * 8192];
    int tid = threadIdx.x;
    int lane = tid & 63, wc = tid >> 6;
    int bm = blockIdx.x * 64;
    f32x4 acc[4][4] = {};
    int srcslot = ((lane & 3) ^ ((lane >> 2) & 3) ^ ((lane >> 4) & 3)) << 3;
    int lrow = lane >> 2;

    auto stage = [&](int t) {
        int k0 = t * 32, sb = t % 3;
        int ra = bm + wc * 16 + lrow; ra = ra < M ? ra : M - 1;
        GLOAD16(A + (size_t)ra * K + k0 + srcslot,
                (char*)As + sb * 4096 + wc * 1024);
        #pragma unroll
        for (int i = 0; i < 4; ++i) {
            int cc = i * 64 + wc * 16 + lrow;
            GLOAD16(Bt + (size_t)cc * K + k0 + srcslot,
                    (char*)Bs + sb * 16384 + i * 4096 + wc * 1024);
        }
    };

    int KT = K >> 5;
    stage(0); stage(1); stage(2);

    int rlo = lane & 15, khalf = lane >> 4;
    int fsl = ((khalf ^ (rlo & 3) ^ ((rlo >> 2) & 3)) << 3);

    for (int t = 0; t < KT; ++t) {
        if (t + 2 < KT)      asm volatile("s_waitcnt vmcnt(10)" ::: "memory");
        else if (t + 1 < KT) asm volatile("s_waitcnt vmcnt(5)" ::: "memory");
        else                 asm volatile("s_waitcnt vmcnt(0)" ::: "memory");
        __builtin_amdgcn_s_barrier();
        __builtin_amdgcn_sched_barrier(0);

        const u16* a_lds = As + (t % 3) * 2048;
        const u16* b_lds = Bs + (t % 3) * 8192;
        short8 af[4], bf_[4];
        #pragma unroll
        for (int mi = 0; mi < 4; ++mi)
            af[mi] = *(const short8*)(a_lds + (mi * 16 + rlo) * 32 + fsl);
        #pragma unroll
        for (int ni = 0; ni < 4; ++ni)
            bf_[ni] = *(const short8*)(b_lds + (wc * 64 + ni * 16 + rlo) * 32 + fsl);

        __builtin_amdgcn_s_setprio(1);
        #pragma unroll
        for (int mi = 0; mi < 4; ++mi)
            #pragma unroll
            for (int ni = 0; ni < 4; ++ni)
                acc[mi][ni] = __builtin_amdgcn_mfma_f32_16x16x32_bf16(
                    af[mi], bf_[ni], acc[mi][ni], 0, 0, 0);
        __builtin_amdgcn_s_setprio(0);

        __builtin_amdgcn_sched_barrier(0);
        asm volatile("s_waitcnt lgkmcnt(0)" ::: "memory");
        __builtin_amdgcn_s_barrier();
        if (t + 3 < KT) stage(t + 3);
    }
    __syncthreads();

    float* red = (float*)As;
    int col_l = lane & 15, rgrp = lane >> 4;
    int colc[4]; float bias_c[4], g_c[4], be_c[4];
    #pragma unroll
    for (int ni = 0; ni < 4; ++ni) {
        colc[ni] = wc * 64 + ni * 16 + col_l;
        bias_c[ni] = bias[colc[ni]];
        g_c[ni]  = g[colc[ni]];
        be_c[ni] = beta[colc[ni]];
    }
    #pragma unroll
    for (int mi = 0; mi < 4; ++mi) {
        #pragma unroll
        for (int j = 0; j < 4; ++j) {
            int rl = mi * 16 + rgrp * 4 + j;
            int row = bm + rl;
            float s = 0.f, s2 = 0.f;
            if (row < M) {
                #pragma unroll
                for (int ni = 0; ni < 4; ++ni) {
                    float v = acc[mi][ni][j] + bias_c[ni] + res[(size_t)row * 256 + colc[ni]];
                    acc[mi][ni][j] = v;
                    s += v; s2 += v * v;
                }
            }
            #pragma unroll
            for (int d = 1; d < 16; d <<= 1) { s += __shfl_xor(s, d); s2 += __shfl_xor(s2, d); }
            if (col_l == 0) { red[wc * 64 + rl] = s; red[256 + wc * 64 + rl] = s2; }
        }
    }
    __syncthreads();
    if (tid < 64) {
        float s  = red[tid] + red[64 + tid] + red[128 + tid] + red[192 + tid];
        float s2 = red[256 + tid] + red[320 + tid] + red[384 + tid] + red[448 + tid];
        float mean = s * (1.f / 256.f);
        float var = s2 * (1.f / 256.f) - mean * mean;
        red[512 + tid] = mean;
        red[576 + tid] = rsqrtf(var + 1e-5f);
    }
    __syncthreads();
    #pragma unroll
    for (int mi = 0; mi < 4; ++mi) {
        #pragma unroll
        for (int j = 0; j < 4; ++j) {
            int rl = mi * 16 + rgrp * 4 + j;
            int row = bm + rl;
            if (row >= M) continue;
            float mean = red[512 + rl], rs = red[576 + rl];
            #pragma unroll
            for (int ni = 0; ni < 4; ++ni) {
                float o = g_c[ni] * (acc[mi][ni][j] - mean) * rs + be_c[ni];
                outf[(size_t)row * 256 + colc[ni]] = o;
                if (outb) outb[(size_t)row * 256 + colc[ni]] = f2bf(o);
            }
        }
    }
}

// ---- deformable sampling: phase-split, byte-offset records, packed-pair FMA ----
__global__ __launch_bounds__(256) void ms_sample(
    const u16* __restrict__ value, const float* __restrict__ oa,
    const float* __restrict__ refp, u16* __restrict__ out)
{
    const int starts[4] = {0, 8464, 10580, 11109};
    const int sizes[4]  = {92, 46, 23, 12};
    int t = threadIdx.x;
    int wv = t >> 6, lane = t & 63;
    int n = blockIdx.x * 4 + wv;

    __shared__ uint4  s_ad[4][128];   // BYTE offsets
    __shared__ float4 s_wt[4][128];

    if (n < N_TOK) {
        const float* oan = oa + (size_t)n * 384;
        unsigned int tokbase = (n >= LEN) ? (unsigned)LEN : 0u;
        #pragma unroll
        for (int rep = 0; rep < 2; ++rep) {
            int q = rep * 64 + lane;          // q = h*16 + pt
            int h = q >> 4, pt = q & 15, l = pt >> 2;
            float logit = oan[256 + q];
            float m = logit;
            #pragma unroll
            for (int d = 1; d < 16; d <<= 1) m = fmaxf(m, __shfl_xor(m, d));
            float e = expf(logit - m);
            float ssum = e;
            #pragma unroll
            for (int d = 1; d < 16; d <<= 1) ssum += __shfl_xor(ssum, d);
            float aw = e / ssum;
            float2 off2 = *(const float2*)(oan + 2 * q);
            float2 ref2 = *(const float2*)(refp + (size_t)n * 8 + l * 2);
            int wl = sizes[l];
            float wf = (float)wl;
            float x = ref2.x * wf - 0.5f + off2.x;
            float y = ref2.y * wf - 0.5f + off2.y;
            float x0f = floorf(x), y0f = floorf(y);
            float fx = x - x0f, fy = y - y0f;
            int x0 = (int)x0f, y0 = (int)y0f;
            int x1 = x0 + 1, y1 = y0 + 1;
            float gx = 1.f - fx, gy = 1.f - fy;
            bool bx0 = (unsigned)x0 < (unsigned)wl, bx1 = (unsigned)x1 < (unsigned)wl;
            bool by0 = (unsigned)y0 < (unsigned)wl, by1 = (unsigned)y1 < (unsigned)wl;
            float w00 = (bx0 && by0) ? gx * gy * aw : 0.f;
            float w10 = (bx1 && by0) ? fx * gy * aw : 0.f;
            float w01 = (bx0 && by1) ? gx * fy * aw : 0.f;
            float w11 = (bx1 && by1) ? fx * fy * aw : 0.f;
            int x0c = min(max(x0, 0), wl - 1), x1c = min(max(x1, 0), wl - 1);
            int y0c = min(max(y0, 0), wl - 1), y1c = min(max(y1, 0), wl - 1);
            // byte offsets: token stride 512 B, head stride 64 B
            unsigned int base = (tokbase + (unsigned)starts[l]) * 512u + (unsigned)(h * 64);
            unsigned int r0 = base + (unsigned)(y0c * wl) * 512u;
            unsigned int r1 = base + (unsigned)(y1c * wl) * 512u;
            int idx = pt * 8 + (h ^ (pt & 7));
            s_ad[wv][idx] = make_uint4(r0 + (unsigned)x0c * 512u, r0 + (unsigned)x1c * 512u,
                                       r1 + (unsigned)x0c * 512u, r1 + (unsigned)x1c * 512u);
            s_wt[wv][idx] = make_float4(w00, w10, w01, w11);
        }
    }
    __syncthreads();
    if (n >= N_TOK) return;

    int h = lane >> 3, dq = lane & 7;
    const char* vb = (const char*)value + dq * 8;   // per-lane 4-dim slice base
    f32x2 acc01 = {0.f, 0.f}, acc23 = {0.f, 0.f};

    #pragma unroll 8
    for (int pt = 0; pt < 16; ++pt) {
        int idx = pt * 8 + (h ^ (pt & 7));
        uint4 ad = s_ad[wv][idx];
        float4 wt = s_wt[wv][idx];
        uint2 u00 = *(const uint2*)(vb + ad.x);
        uint2 u10 = *(const uint2*)(vb + ad.y);
        uint2 u01 = *(const uint2*)(vb + ad.z);
        uint2 u11 = *(const uint2*)(vb + ad.w);
        acc01 += wt.x * bf2x2(u00.x); acc23 += wt.x * bf2x2(u00.y);
        acc01 += wt.y * bf2x2(u10.x); acc23 += wt.y * bf2x2(u10.y);
        acc01 += wt.z * bf2x2(u01.x); acc23 += wt.z * bf2x2(u01.y);
        acc01 += wt.w * bf2x2(u11.x); acc23 += wt.w * bf2x2(u11.y);
    }
    u16 o[4] = { f2bf(acc01[0]), f2bf(acc01[1]), f2bf(acc23[0]), f2bf(acc23[1]) };
    *(ushort4*)(out + (size_t)n * 256 + h * 32 + dq * 4) = *(ushort4*)o;
}

extern "C" void kernel_launch(void* const* d_in, const int* in_sizes, int n_in,
                              void* d_out, int out_size, void* d_ws, size_t ws_size,
                              hipStream_t stream) {
    const float* src    = (const float*)d_in[0];
    const float* pos    = (const float*)d_in[1];
    const float* refp   = (const float*)d_in[2];
    const float* w_value= (const float*)d_in[3];
    const float* b_value= (const float*)d_in[4];
    const float* w_off  = (const float*)d_in[5];
    const float* b_off  = (const float*)d_in[6];
    const float* w_attn = (const float*)d_in[7];
    const float* b_attn = (const float*)d_in[8];
    const float* w_out  = (const float*)d_in[9];
    const float* b_out  = (const float*)d_in[10];
    const float* ln1_g  = (const float*)d_in[11];
    const float* ln1_b  = (const float*)d_in[12];
    const float* w1     = (const float*)d_in[13];
    const float* b1     = (const float*)d_in[14];
    const float* w2     = (const float*)d_in[15];
    const float* b2     = (const float*)d_in[16];
    const float* ln2_g  = (const float*)d_in[17];
    const float* ln2_b  = (const float*)d_in[18];

    // ws layout (bytes), liveness-packed:
    //   srcb [0, 11523072)         bf16; dead after gemm5; then Sb
    //   Vb   [11523072, 23046144)  bf16; dead after sample
    //   qb   [23046144, 34569216)  bf16; dead after gemm5
    //   X    [11523072, 34569216)  f32  LN1 out (overlay)
    //   OA   [34569216, 69138432)  f32; dead after sample
    //   Xb   [34569216, 46092288)  bf16 LN1 out (overlay)
    //   Hb   [46092288, 92184576)  bf16 FFN hidden
    //   weights [92184576, ...)
    char* w = (char*)d_ws;
    u16*   srcb = (u16*)w;
    u16*   Sb   = srcb;
    u16*   Vb   = (u16*)(w + 11523072);
    u16*   qb   = (u16*)(w + 23046144);
    float* X    = (float*)(w + 11523072);
    float* OA   = (float*)(w + 34569216);
    u16*   Xb   = (u16*)(w + 34569216);
    u16*   Hb   = (u16*)(w + 46092288);
    char*  WB   = w + 92184576;
    u16* wv_t   = (u16*)WB;
    u16* woa_t  = wv_t + 65536;
    u16* wout_t = woa_t + 98304;
    u16* w1_t   = wout_t + 65536;
    u16* w2_t   = w1_t + 262144;
    float* boa  = (float*)(w2_t + 262144);
    float* out  = (float*)d_out;

    dim3 b256(256);
    int MB = (N_TOK + 127) / 128;   // 176

    // weights + bias + src/q bf16 conversion, one dispatch
    wprep<<<dim3(8572), b256, 0, stream>>>(w_value, w_off, w_attn, w_out, w1, w2,
                                           b_off, b_attn, src, pos,
                                           wv_t, woa_t, wout_t, w1_t, w2_t, boa, srcb, qb);
    // value(bf16) + [off|attn](f32), fused: 5 panels x 176 tiles
    gemm5<<<dim3(5 * MB), b256, 0, stream>>>(srcb, qb, wv_t, woa_t, b_value, boa, Vb, OA);
    // sampling (fused softmax) -> Sb bf16 (reuses srcb)
    ms_sample<<<dim3((N_TOK + 3) / 4), b256, 0, stream>>>(Vb, OA, refp, Sb);
    // x = LN1(src + Sb @ w_out + b_out) -> X f32, Xb bf16
    gemm_ln<<<dim3((N_TOK + 63) / 64), b256, 0, stream>>>(Sb, wout_t, b_out, src,
                                                          ln1_g, ln1_b, X, Xb, N_TOK, 256);
    // hidden = relu(Xb @ w1 + b1) -> Hb bf16
    gemm2<<<dim3(8, MB), b256, 0, stream>>>(Xb, w1_t, b1, nullptr, Hb, N_TOK, 1024, 256, 1);
    // out = LN2(X + Hb @ w2 + b2) -> d_out f32
    gemm_ln<<<dim3((N_TOK + 63) / 64), b256, 0, stream>>>(Hb, w2_t, b2, X,
                                                          ln2_g, ln2_b, out, nullptr, N_TOK, 1024);
}

// Round 11
// 208.674 us; speedup vs baseline: 1.3200x; 1.0039x over previous
//
#include <hip/hip_runtime.h>
#include <hip/hip_bf16.h>
#include <math.h>

#define N_TOK 22506
#define LEN   11253

typedef unsigned short u16;
typedef __attribute__((ext_vector_type(8))) short short8;
typedef __attribute__((ext_vector_type(4))) float f32x4;
typedef __attribute__((ext_vector_type(2))) float f32x2;
typedef __attribute__((ext_vector_type(2))) unsigned int u32x2;

#define GLOAD16(g, l) __builtin_amdgcn_global_load_lds( \
    (const __attribute__((address_space(1))) void*)(g), \
    (__attribute__((address_space(3))) void*)(l), 16, 0, 0)

static __device__ __forceinline__ u16 f2bf(float f) {
    unsigned int u = __builtin_bit_cast(unsigned int, f);
    u = (u + 0x7fffu + ((u >> 16) & 1u)) >> 16;
    return (u16)u;
}
// unpack 2 bf16 (one dword) -> f32 pair
static __device__ __forceinline__ f32x2 bf2x2(unsigned int a) {
    u32x2 t = { a << 16, a & 0xffff0000u };
    return __builtin_bit_cast(f32x2, t);
}

// bijective XCD-chunked swizzle (m204)
static __device__ __forceinline__ int xcd_swz(int id, int nwg) {
    int q = nwg >> 3, r = nwg & 7;
    int xcd = id & 7, rank = id >> 3;
    return (xcd < r ? xcd * (q + 1) : r * (q + 1) + (xcd - r) * q) + rank;
}

// ---- weight transposes + bias concat + src/q bf16 conversion, one dispatch ----
__global__ __launch_bounds__(256) void wprep(
    const float* __restrict__ w_value, const float* __restrict__ w_off,
    const float* __restrict__ w_attn, const float* __restrict__ w_out,
    const float* __restrict__ w1, const float* __restrict__ w2,
    const float* __restrict__ b_off, const float* __restrict__ b_attn,
    const float* __restrict__ src, const float* __restrict__ pos,
    u16* __restrict__ wv_t, u16* __restrict__ woa_t, u16* __restrict__ wout_t,
    u16* __restrict__ w1_t, u16* __restrict__ w2_t, float* __restrict__ boa,
    u16* __restrict__ srcb, u16* __restrict__ qb)
{
    int i = blockIdx.x * 256 + threadIdx.x;
    if (i < 65536) {
        wv_t[(i & 255) * 256 + (i >> 8)] = f2bf(w_value[i]);
    } else if (i < 131072) {
        int j = i - 65536;
        woa_t[(j & 255) * 256 + (j >> 8)] = f2bf(w_off[j]);
    } else if (i < 163840) {
        int j = i - 131072;
        woa_t[65536 + (j & 127) * 256 + (j >> 7)] = f2bf(w_attn[j]);
    } else if (i < 229376) {
        int j = i - 163840;
        wout_t[(j & 255) * 256 + (j >> 8)] = f2bf(w_out[j]);
    } else if (i < 491520) {
        int j = i - 229376;
        w1_t[(j & 1023) * 256 + (j >> 10)] = f2bf(w1[j]);
    } else if (i < 753664) {
        int j = i - 491520;
        w2_t[(j & 255) * 1024 + (j >> 8)] = f2bf(w2[j]);
    } else if (i < 754048) {
        int j = i - 753664;
        boa[j] = (j < 256) ? b_off[j] : b_attn[j - 256];
    } else if (i < 754048 + 1440384) {
        int j = i - 754048;                 // float4 index over N_TOK*256
        float4 s = ((const float4*)src)[j];
        float4 p = ((const float4*)pos)[j];
        u16 sb[4] = { f2bf(s.x), f2bf(s.y), f2bf(s.z), f2bf(s.w) };
        u16 q4[4] = { f2bf(s.x + p.x), f2bf(s.y + p.y), f2bf(s.z + p.z), f2bf(s.w + p.w) };
        *(ushort4*)(srcb + (size_t)j * 4) = *(ushort4*)sb;
        *(ushort4*)(qb + (size_t)j * 4) = *(ushort4*)q4;
    }
}

// ============ fused value + off/attn GEMM: 128x128 tile, BK=32, 3-deep ============
__global__ __launch_bounds__(256) void gemm5(
    const u16* __restrict__ srcb, const u16* __restrict__ qb,
    const u16* __restrict__ wv_t, const u16* __restrict__ woa_t,
    const float* __restrict__ b_value, const float* __restrict__ boa,
    u16* __restrict__ Vb, float* __restrict__ OA)
{
    __shared__ u16 As[3 * 4096];
    __shared__ u16 Bs[3 * 4096];
    int tid = threadIdx.x;
    int lane = tid & 63, wid = tid >> 6;
    int wr = wid >> 1, wc = wid & 1;

    int sid = xcd_swz(blockIdx.x, gridDim.x);
    int p = sid % 5, bm = (sid / 5) * 128;
    int job = p < 2 ? 0 : 1;
    int bn = job ? (p - 2) * 128 : p * 128;
    const u16* A  = job ? qb : srcb;
    const u16* Bt = job ? woa_t : wv_t;

    f32x4 acc[4][4] = {};
    int srcslot = ((lane & 3) ^ ((lane >> 2) & 3) ^ ((lane >> 4) & 3)) << 3;
    int lrow = lane >> 2;

    auto stage = [&](int t) {
        int k0 = t * 32, sb = t % 3;
        #pragma unroll
        for (int c = 0; c < 2; ++c) {
            int rr = wid * 32 + c * 16 + lrow;
            int ra = bm + rr; ra = ra < N_TOK ? ra : N_TOK - 1;
            GLOAD16(A + (size_t)ra * 256 + k0 + srcslot,
                    (char*)As + sb * 8192 + wid * 2048 + c * 1024);
            GLOAD16(Bt + (size_t)(bn + rr) * 256 + k0 + srcslot,
                    (char*)Bs + sb * 8192 + wid * 2048 + c * 1024);
        }
    };

    stage(0); stage(1); stage(2);

    int rlo = lane & 15, khalf = lane >> 4;
    int fsl = ((khalf ^ (rlo & 3) ^ ((rlo >> 2) & 3)) << 3);

    for (int t = 0; t < 8; ++t) {
        if (t + 2 < 8)      asm volatile("s_waitcnt vmcnt(8)" ::: "memory");
        else if (t + 1 < 8) asm volatile("s_waitcnt vmcnt(4)" ::: "memory");
        else                asm volatile("s_waitcnt vmcnt(0)" ::: "memory");
        __builtin_amdgcn_s_barrier();
        __builtin_amdgcn_sched_barrier(0);

        const u16* a_lds = As + (t % 3) * 4096;
        const u16* b_lds = Bs + (t % 3) * 4096;
        short8 af[4], bf_[4];
        #pragma unroll
        for (int mi = 0; mi < 4; ++mi)
            af[mi] = *(const short8*)(a_lds + (wr * 64 + mi * 16 + rlo) * 32 + fsl);
        #pragma unroll
        for (int ni = 0; ni < 4; ++ni)
            bf_[ni] = *(const short8*)(b_lds + (wc * 64 + ni * 16 + rlo) * 32 + fsl);

        __builtin_amdgcn_s_setprio(1);
        #pragma unroll
        for (int mi = 0; mi < 4; ++mi)
            #pragma unroll
            for (int ni = 0; ni < 4; ++ni)
                acc[mi][ni] = __builtin_amdgcn_mfma_f32_16x16x32_bf16(
                    af[mi], bf_[ni], acc[mi][ni], 0, 0, 0);
        __builtin_amdgcn_s_setprio(0);

        __builtin_amdgcn_sched_barrier(0);
        asm volatile("s_waitcnt lgkmcnt(0)" ::: "memory");
        __builtin_amdgcn_s_barrier();
        if (t + 3 < 8) stage(t + 3);
    }

    int col_l = lane & 15, rgrp = lane >> 4;
    #pragma unroll
    for (int mi = 0; mi < 4; ++mi) {
        #pragma unroll
        for (int j = 0; j < 4; ++j) {
            int row = bm + wr * 64 + mi * 16 + rgrp * 4 + j;
            if (row >= N_TOK) continue;
            #pragma unroll
            for (int ni = 0; ni < 4; ++ni) {
                int col = bn + wc * 64 + ni * 16 + col_l;
                if (job) OA[(size_t)row * 384 + col] = acc[mi][ni][j] + boa[col];
                else     Vb[(size_t)row * 256 + col] = f2bf(acc[mi][ni][j] + b_value[col]);
            }
        }
    }
}

// ============ pipelined bf16 MFMA GEMM: 128x128 tile, BK=32, 3-deep (FFN1) ============
__global__ __launch_bounds__(256) void gemm2(
    const u16* __restrict__ A, const u16* __restrict__ Bt,
    const float* __restrict__ bias, float* __restrict__ Cf, u16* __restrict__ Cb,
    int M, int Nc, int K, int relu)
{
    __shared__ u16 As[3 * 4096];
    __shared__ u16 Bs[3 * 4096];
    int tid = threadIdx.x;
    int lane = tid & 63, wid = tid >> 6;
    int wr = wid >> 1, wc = wid & 1;

    int nwg = gridDim.x * gridDim.y;
    int sid = xcd_swz(blockIdx.y * gridDim.x + blockIdx.x, nwg);
    int bm = (sid / gridDim.x) * 128, bn = (sid % gridDim.x) * 128;

    f32x4 acc[4][4] = {};
    int srcslot = ((lane & 3) ^ ((lane >> 2) & 3) ^ ((lane >> 4) & 3)) << 3;
    int lrow = lane >> 2;

    auto stage = [&](int t) {
        int k0 = t * 32, sb = t % 3;
        #pragma unroll
        for (int c = 0; c < 2; ++c) {
            int rr = wid * 32 + c * 16 + lrow;
            int ra = bm + rr; ra = ra < M ? ra : M - 1;
            GLOAD16(A + (size_t)ra * K + k0 + srcslot,
                    (char*)As + sb * 8192 + wid * 2048 + c * 1024);
            GLOAD16(Bt + (size_t)(bn + rr) * K + k0 + srcslot,
                    (char*)Bs + sb * 8192 + wid * 2048 + c * 1024);
        }
    };

    int KT = K >> 5;
    stage(0); stage(1); stage(2);

    int rlo = lane & 15, khalf = lane >> 4;
    int fsl = ((khalf ^ (rlo & 3) ^ ((rlo >> 2) & 3)) << 3);

    for (int t = 0; t < KT; ++t) {
        if (t + 2 < KT)      asm volatile("s_waitcnt vmcnt(8)" ::: "memory");
        else if (t + 1 < KT) asm volatile("s_waitcnt vmcnt(4)" ::: "memory");
        else                 asm volatile("s_waitcnt vmcnt(0)" ::: "memory");
        __builtin_amdgcn_s_barrier();
        __builtin_amdgcn_sched_barrier(0);

        const u16* a_lds = As + (t % 3) * 4096;
        const u16* b_lds = Bs + (t % 3) * 4096;
        short8 af[4], bf_[4];
        #pragma unroll
        for (int mi = 0; mi < 4; ++mi)
            af[mi] = *(const short8*)(a_lds + (wr * 64 + mi * 16 + rlo) * 32 + fsl);
        #pragma unroll
        for (int ni = 0; ni < 4; ++ni)
            bf_[ni] = *(const short8*)(b_lds + (wc * 64 + ni * 16 + rlo) * 32 + fsl);

        __builtin_amdgcn_s_setprio(1);
        #pragma unroll
        for (int mi = 0; mi < 4; ++mi)
            #pragma unroll
            for (int ni = 0; ni < 4; ++ni)
                acc[mi][ni] = __builtin_amdgcn_mfma_f32_16x16x32_bf16(
                    af[mi], bf_[ni], acc[mi][ni], 0, 0, 0);
        __builtin_amdgcn_s_setprio(0);

        __builtin_amdgcn_sched_barrier(0);
        asm volatile("s_waitcnt lgkmcnt(0)" ::: "memory");
        __builtin_amdgcn_s_barrier();
        if (t + 3 < KT) stage(t + 3);
    }

    int col_l = lane & 15, rgrp = lane >> 4;
    #pragma unroll
    for (int mi = 0; mi < 4; ++mi) {
        #pragma unroll
        for (int j = 0; j < 4; ++j) {
            int row = bm + wr * 64 + mi * 16 + rgrp * 4 + j;
            if (row >= M) continue;
            #pragma unroll
            for (int ni = 0; ni < 4; ++ni) {
                int col = bn + wc * 64 + ni * 16 + col_l;
                float v = acc[mi][ni][j];
                if (bias) v += bias[col];
                if (relu) v = fmaxf(v, 0.f);
                if (Cf) Cf[(size_t)row * Nc + col] = v;
                if (Cb) Cb[(size_t)row * Nc + col] = f2bf(v);
            }
        }
    }
}

// ============ pipelined Nc=256 GEMM + residual + LayerNorm, BK=32, 3-deep ============
__global__ __launch_bounds__(256) void gemm_ln(
    const u16* __restrict__ A, const u16* __restrict__ Bt,
    const float* __restrict__ bias, const float* __restrict__ res,
    const float* __restrict__ g, const float* __restrict__ beta,
    float* __restrict__ outf, u16* __restrict__ outb,
    int M, int K)
{
    __shared__ u16 As[3 * 2048];
    __shared__ u16 Bs[3 * 8192];
    int tid = threadIdx.x;
    int lane = tid & 63, wc = tid >> 6;
    int bm = blockIdx.x * 64;
    f32x4 acc[4][4] = {};
    int srcslot = ((lane & 3) ^ ((lane >> 2) & 3) ^ ((lane >> 4) & 3)) << 3;
    int lrow = lane >> 2;

    auto stage = [&](int t) {
        int k0 = t * 32, sb = t % 3;
        int ra = bm + wc * 16 + lrow; ra = ra < M ? ra : M - 1;
        GLOAD16(A + (size_t)ra * K + k0 + srcslot,
                (char*)As + sb * 4096 + wc * 1024);
        #pragma unroll
        for (int i = 0; i < 4; ++i) {
            int cc = i * 64 + wc * 16 + lrow;
            GLOAD16(Bt + (size_t)cc * K + k0 + srcslot,
                    (char*)Bs + sb * 16384 + i * 4096 + wc * 1024);
        }
    };

    int KT = K >> 5;
    stage(0); stage(1); stage(2);

    int rlo = lane & 15, khalf = lane >> 4;
    int fsl = ((khalf ^ (rlo & 3) ^ ((rlo >> 2) & 3)) << 3);

    for (int t = 0; t < KT; ++t) {
        if (t + 2 < KT)      asm volatile("s_waitcnt vmcnt(10)" ::: "memory");
        else if (t + 1 < KT) asm volatile("s_waitcnt vmcnt(5)" ::: "memory");
        else                 asm volatile("s_waitcnt vmcnt(0)" ::: "memory");
        __builtin_amdgcn_s_barrier();
        __builtin_amdgcn_sched_barrier(0);

        const u16* a_lds = As + (t % 3) * 2048;
        const u16* b_lds = Bs + (t % 3) * 8192;
        short8 af[4], bf_[4];
        #pragma unroll
        for (int mi = 0; mi < 4; ++mi)
            af[mi] = *(const short8*)(a_lds + (mi * 16 + rlo) * 32 + fsl);
        #pragma unroll
        for (int ni = 0; ni < 4; ++ni)
            bf_[ni] = *(const short8*)(b_lds + (wc * 64 + ni * 16 + rlo) * 32 + fsl);

        __builtin_amdgcn_s_setprio(1);
        #pragma unroll
        for (int mi = 0; mi < 4; ++mi)
            #pragma unroll
            for (int ni = 0; ni < 4; ++ni)
                acc[mi][ni] = __builtin_amdgcn_mfma_f32_16x16x32_bf16(
                    af[mi], bf_[ni], acc[mi][ni], 0, 0, 0);
        __builtin_amdgcn_s_setprio(0);

        __builtin_amdgcn_sched_barrier(0);
        asm volatile("s_waitcnt lgkmcnt(0)" ::: "memory");
        __builtin_amdgcn_s_barrier();
        if (t + 3 < KT) stage(t + 3);
    }
    __syncthreads();

    float* red = (float*)As;
    int col_l = lane & 15, rgrp = lane >> 4;
    int colc[4]; float bias_c[4], g_c[4], be_c[4];
    #pragma unroll
    for (int ni = 0; ni < 4; ++ni) {
        colc[ni] = wc * 64 + ni * 16 + col_l;
        bias_c[ni] = bias[colc[ni]];
        g_c[ni]  = g[colc[ni]];
        be_c[ni] = beta[colc[ni]];
    }
    #pragma unroll
    for (int mi = 0; mi < 4; ++mi) {
        #pragma unroll
        for (int j = 0; j < 4; ++j) {
            int rl = mi * 16 + rgrp * 4 + j;
            int row = bm + rl;
            float s = 0.f, s2 = 0.f;
            if (row < M) {
                #pragma unroll
                for (int ni = 0; ni < 4; ++ni) {
                    float v = acc[mi][ni][j] + bias_c[ni] + res[(size_t)row * 256 + colc[ni]];
                    acc[mi][ni][j] = v;
                    s += v; s2 += v * v;
                }
            }
            #pragma unroll
            for (int d = 1; d < 16; d <<= 1) { s += __shfl_xor(s, d); s2 += __shfl_xor(s2, d); }
            if (col_l == 0) { red[wc * 64 + rl] = s; red[256 + wc * 64 + rl] = s2; }
        }
    }
    __syncthreads();
    if (tid < 64) {
        float s  = red[tid] + red[64 + tid] + red[128 + tid] + red[192 + tid];
        float s2 = red[256 + tid] + red[320 + tid] + red[384 + tid] + red[448 + tid];
        float mean = s * (1.f / 256.f);
        float var = s2 * (1.f / 256.f) - mean * mean;
        red[512 + tid] = mean;
        red[576 + tid] = rsqrtf(var + 1e-5f);
    }
    __syncthreads();
    #pragma unroll
    for (int mi = 0; mi < 4; ++mi) {
        #pragma unroll
        for (int j = 0; j < 4; ++j) {
            int rl = mi * 16 + rgrp * 4 + j;
            int row = bm + rl;
            if (row >= M) continue;
            float mean = red[512 + rl], rs = red[576 + rl];
            #pragma unroll
            for (int ni = 0; ni < 4; ++ni) {
                float o = g_c[ni] * (acc[mi][ni][j] - mean) * rs + be_c[ni];
                outf[(size_t)row * 256 + colc[ni]] = o;
                if (outb) outb[(size_t)row * 256 + colc[ni]] = f2bf(o);
            }
        }
    }
}

// ---- deformable sampling: phase-split, 3-slot pipelined gather, 8 acc chains ----
__global__ __launch_bounds__(256) void ms_sample(
    const u16* __restrict__ value, const float* __restrict__ oa,
    const float* __restrict__ refp, u16* __restrict__ out)
{
    const int starts[4] = {0, 8464, 10580, 11109};
    const int sizes[4]  = {92, 46, 23, 12};
    int t = threadIdx.x;
    int wv = t >> 6, lane = t & 63;
    int n = blockIdx.x * 4 + wv;

    __shared__ uint4  s_ad[4][128];   // BYTE offsets
    __shared__ float4 s_wt[4][128];

    if (n < N_TOK) {
        const float* oan = oa + (size_t)n * 384;
        unsigned int tokbase = (n >= LEN) ? (unsigned)LEN : 0u;
        #pragma unroll
        for (int rep = 0; rep < 2; ++rep) {
            int q = rep * 64 + lane;          // q = h*16 + pt
            int h = q >> 4, pt = q & 15, l = pt >> 2;
            float logit = oan[256 + q];
            float m = logit;
            #pragma unroll
            for (int d = 1; d < 16; d <<= 1) m = fmaxf(m, __shfl_xor(m, d));
            float e = expf(logit - m);
            float ssum = e;
            #pragma unroll
            for (int d = 1; d < 16; d <<= 1) ssum += __shfl_xor(ssum, d);
            float aw = e / ssum;
            float2 off2 = *(const float2*)(oan + 2 * q);
            float2 ref2 = *(const float2*)(refp + (size_t)n * 8 + l * 2);
            int wl = sizes[l];
            float wf = (float)wl;
            float x = ref2.x * wf - 0.5f + off2.x;
            float y = ref2.y * wf - 0.5f + off2.y;
            float x0f = floorf(x), y0f = floorf(y);
            float fx = x - x0f, fy = y - y0f;
            int x0 = (int)x0f, y0 = (int)y0f;
            int x1 = x0 + 1, y1 = y0 + 1;
            float gx = 1.f - fx, gy = 1.f - fy;
            bool bx0 = (unsigned)x0 < (unsigned)wl, bx1 = (unsigned)x1 < (unsigned)wl;
            bool by0 = (unsigned)y0 < (unsigned)wl, by1 = (unsigned)y1 < (unsigned)wl;
            float w00 = (bx0 && by0) ? gx * gy * aw : 0.f;
            float w10 = (bx1 && by0) ? fx * gy * aw : 0.f;
            float w01 = (bx0 && by1) ? gx * fy * aw : 0.f;
            float w11 = (bx1 && by1) ? fx * fy * aw : 0.f;
            int x0c = min(max(x0, 0), wl - 1), x1c = min(max(x1, 0), wl - 1);
            int y0c = min(max(y0, 0), wl - 1), y1c = min(max(y1, 0), wl - 1);
            unsigned int base = (tokbase + (unsigned)starts[l]) * 512u + (unsigned)(h * 64);
            unsigned int r0 = base + (unsigned)(y0c * wl) * 512u;
            unsigned int r1 = base + (unsigned)(y1c * wl) * 512u;
            int idx = pt * 8 + (h ^ (pt & 7));
            s_ad[wv][idx] = make_uint4(r0 + (unsigned)x0c * 512u, r0 + (unsigned)x1c * 512u,
                                       r1 + (unsigned)x0c * 512u, r1 + (unsigned)x1c * 512u);
            s_wt[wv][idx] = make_float4(w00, w10, w01, w11);
        }
    }
    __syncthreads();
    if (n >= N_TOK) return;

    int h = lane >> 3, dq = lane & 7;
    const char* vb = (const char*)value + dq * 8;

    // 3-slot software pipeline: 12 gathers in flight; 8 independent acc chains
    uint2 v00[3], v10[3], v01[3], v11[3];
    float4 wt[3];
    f32x2 c0a = {0,0}, c0b = {0,0}, c1a = {0,0}, c1b = {0,0};
    f32x2 c2a = {0,0}, c2b = {0,0}, c3a = {0,0}, c3b = {0,0};

    #pragma unroll
    for (int pt = 0; pt < 3; ++pt) {
        int idx = pt * 8 + (h ^ (pt & 7));
        uint4 ad = s_ad[wv][idx];
        wt[pt] = s_wt[wv][idx];
        v00[pt] = *(const uint2*)(vb + ad.x);
        v10[pt] = *(const uint2*)(vb + ad.y);
        v01[pt] = *(const uint2*)(vb + ad.z);
        v11[pt] = *(const uint2*)(vb + ad.w);
    }
    #pragma unroll
    for (int pt = 0; pt < 16; ++pt) {
        int s = pt % 3;
        c0a += wt[s].x * bf2x2(v00[s].x); c0b += wt[s].x * bf2x2(v00[s].y);
        c1a += wt[s].y * bf2x2(v10[s].x); c1b += wt[s].y * bf2x2(v10[s].y);
        c2a += wt[s].z * bf2x2(v01[s].x); c2b += wt[s].z * bf2x2(v01[s].y);
        c3a += wt[s].w * bf2x2(v11[s].x); c3b += wt[s].w * bf2x2(v11[s].y);
        if (pt + 3 < 16) {
            int np = pt + 3;
            int idx = np * 8 + (h ^ (np & 7));
            uint4 ad = s_ad[wv][idx];
            wt[s] = s_wt[wv][idx];
            v00[s] = *(const uint2*)(vb + ad.x);
            v10[s] = *(const uint2*)(vb + ad.y);
            v01[s] = *(const uint2*)(vb + ad.z);
            v11[s] = *(const uint2*)(vb + ad.w);
        }
    }
    f32x2 acc01 = (c0a + c1a) + (c2a + c3a);
    f32x2 acc23 = (c0b + c1b) + (c2b + c3b);
    u16 o[4] = { f2bf(acc01[0]), f2bf(acc01[1]), f2bf(acc23[0]), f2bf(acc23[1]) };
    *(ushort4*)(out + (size_t)n * 256 + h * 32 + dq * 4) = *(ushort4*)o;
}

extern "C" void kernel_launch(void* const* d_in, const int* in_sizes, int n_in,
                              void* d_out, int out_size, void* d_ws, size_t ws_size,
                              hipStream_t stream) {
    const float* src    = (const float*)d_in[0];
    const float* pos    = (const float*)d_in[1];
    const float* refp   = (const float*)d_in[2];
    const float* w_value= (const float*)d_in[3];
    const float* b_value= (const float*)d_in[4];
    const float* w_off  = (const float*)d_in[5];
    const float* b_off  = (const float*)d_in[6];
    const float* w_attn = (const float*)d_in[7];
    const float* b_attn = (const float*)d_in[8];
    const float* w_out  = (const float*)d_in[9];
    const float* b_out  = (const float*)d_in[10];
    const float* ln1_g  = (const float*)d_in[11];
    const float* ln1_b  = (const float*)d_in[12];
    const float* w1     = (const float*)d_in[13];
    const float* b1     = (const float*)d_in[14];
    const float* w2     = (const float*)d_in[15];
    const float* b2     = (const float*)d_in[16];
    const float* ln2_g  = (const float*)d_in[17];
    const float* ln2_b  = (const float*)d_in[18];

    // ws layout (bytes), liveness-packed:
    //   srcb [0, 11523072)         bf16; dead after gemm5; then Sb
    //   Vb   [11523072, 23046144)  bf16; dead after sample
    //   qb   [23046144, 34569216)  bf16; dead after gemm5
    //   X    [11523072, 34569216)  f32  LN1 out (overlay)
    //   OA   [34569216, 69138432)  f32; dead after sample
    //   Xb   [34569216, 46092288)  bf16 LN1 out (overlay)
    //   Hb   [46092288, 92184576)  bf16 FFN hidden
    //   weights [92184576, ...)
    char* w = (char*)d_ws;
    u16*   srcb = (u16*)w;
    u16*   Sb   = srcb;
    u16*   Vb   = (u16*)(w + 11523072);
    u16*   qb   = (u16*)(w + 23046144);
    float* X    = (float*)(w + 11523072);
    float* OA   = (float*)(w + 34569216);
    u16*   Xb   = (u16*)(w + 34569216);
    u16*   Hb   = (u16*)(w + 46092288);
    char*  WB   = w + 92184576;
    u16* wv_t   = (u16*)WB;
    u16* woa_t  = wv_t + 65536;
    u16* wout_t = woa_t + 98304;
    u16* w1_t   = wout_t + 65536;
    u16* w2_t   = w1_t + 262144;
    float* boa  = (float*)(w2_t + 262144);
    float* out  = (float*)d_out;

    dim3 b256(256);
    int MB = (N_TOK + 127) / 128;   // 176

    wprep<<<dim3(8572), b256, 0, stream>>>(w_value, w_off, w_attn, w_out, w1, w2,
                                           b_off, b_attn, src, pos,
                                           wv_t, woa_t, wout_t, w1_t, w2_t, boa, srcb, qb);
    gemm5<<<dim3(5 * MB), b256, 0, stream>>>(srcb, qb, wv_t, woa_t, b_value, boa, Vb, OA);
    ms_sample<<<dim3((N_TOK + 3) / 4), b256, 0, stream>>>(Vb, OA, refp, Sb);
    gemm_ln<<<dim3((N_TOK + 63) / 64), b256, 0, stream>>>(Sb, wout_t, b_out, src,
                                                          ln1_g, ln1_b, X, Xb, N_TOK, 256);
    gemm2<<<dim3(8, MB), b256, 0, stream>>>(Xb, w1_t, b1, nullptr, Hb, N_TOK, 1024, 256, 1);
    gemm_ln<<<dim3((N_TOK + 63) / 64), b256, 0, stream>>>(Hb, w2_t, b2, X,
                                                          ln2_g, ln2_b, out, nullptr, N_TOK, 1024);
}

// Round 12
// 205.465 us; speedup vs baseline: 1.3406x; 1.0156x over previous
//
#include <hip/hip_runtime.h>
#include <hip/hip_bf16.h>
#include <math.h>

#define N_TOK 22506
#define LEN   11253

typedef unsigned short u16;
typedef __attribute__((ext_vector_type(8))) short short8;
typedef __attribute__((ext_vector_type(4))) float f32x4;
typedef __attribute__((ext_vector_type(2))) float f32x2;
typedef __attribute__((ext_vector_type(2))) unsigned int u32x2;

#define GLOAD16(g, l) __builtin_amdgcn_global_load_lds( \
    (const __attribute__((address_space(1))) void*)(g), \
    (__attribute__((address_space(3))) void*)(l), 16, 0, 0)

static __device__ __forceinline__ u16 f2bf(float f) {
    unsigned int u = __builtin_bit_cast(unsigned int, f);
    u = (u + 0x7fffu + ((u >> 16) & 1u)) >> 16;
    return (u16)u;
}
// unpack 2 bf16 (one dword) -> f32 pair
static __device__ __forceinline__ f32x2 bf2x2(unsigned int a) {
    u32x2 t = { a << 16, a & 0xffff0000u };
    return __builtin_bit_cast(f32x2, t);
}

// bijective XCD-chunked swizzle (m204)
static __device__ __forceinline__ int xcd_swz(int id, int nwg) {
    int q = nwg >> 3, r = nwg & 7;
    int xcd = id & 7, rank = id >> 3;
    return (xcd < r ? xcd * (q + 1) : r * (q + 1) + (xcd - r) * q) + rank;
}

// ---- weight transposes + bias concat + src/q bf16 conversion, one dispatch ----
__global__ __launch_bounds__(256) void wprep(
    const float* __restrict__ w_value, const float* __restrict__ w_off,
    const float* __restrict__ w_attn, const float* __restrict__ w_out,
    const float* __restrict__ w1, const float* __restrict__ w2,
    const float* __restrict__ b_off, const float* __restrict__ b_attn,
    const float* __restrict__ src, const float* __restrict__ pos,
    u16* __restrict__ wv_t, u16* __restrict__ woa_t, u16* __restrict__ wout_t,
    u16* __restrict__ w1_t, u16* __restrict__ w2_t, float* __restrict__ boa,
    u16* __restrict__ srcb, u16* __restrict__ qb)
{
    int i = blockIdx.x * 256 + threadIdx.x;
    if (i < 65536) {
        wv_t[(i & 255) * 256 + (i >> 8)] = f2bf(w_value[i]);
    } else if (i < 131072) {
        int j = i - 65536;
        woa_t[(j & 255) * 256 + (j >> 8)] = f2bf(w_off[j]);
    } else if (i < 163840) {
        int j = i - 131072;
        woa_t[65536 + (j & 127) * 256 + (j >> 7)] = f2bf(w_attn[j]);
    } else if (i < 229376) {
        int j = i - 163840;
        wout_t[(j & 255) * 256 + (j >> 8)] = f2bf(w_out[j]);
    } else if (i < 491520) {
        int j = i - 229376;
        w1_t[(j & 1023) * 256 + (j >> 10)] = f2bf(w1[j]);
    } else if (i < 753664) {
        int j = i - 491520;
        w2_t[(j & 255) * 1024 + (j >> 8)] = f2bf(w2[j]);
    } else if (i < 754048) {
        int j = i - 753664;
        boa[j] = (j < 256) ? b_off[j] : b_attn[j - 256];
    } else if (i < 754048 + 1440384) {
        int j = i - 754048;                 // float4 index over N_TOK*256
        float4 s = ((const float4*)src)[j];
        float4 p = ((const float4*)pos)[j];
        u16 sb[4] = { f2bf(s.x), f2bf(s.y), f2bf(s.z), f2bf(s.w) };
        u16 q4[4] = { f2bf(s.x + p.x), f2bf(s.y + p.y), f2bf(s.z + p.z), f2bf(s.w + p.w) };
        *(ushort4*)(srcb + (size_t)j * 4) = *(ushort4*)sb;
        *(ushort4*)(qb + (size_t)j * 4) = *(ushort4*)q4;
    }
}

// ============ fused value + off/attn GEMM: 128x128 tile, BK=32, 3-deep ============
__global__ __launch_bounds__(256) void gemm5(
    const u16* __restrict__ srcb, const u16* __restrict__ qb,
    const u16* __restrict__ wv_t, const u16* __restrict__ woa_t,
    const float* __restrict__ b_value, const float* __restrict__ boa,
    u16* __restrict__ Vb, float* __restrict__ OA)
{
    __shared__ u16 As[3 * 4096];
    __shared__ u16 Bs[3 * 4096];
    int tid = threadIdx.x;
    int lane = tid & 63, wid = tid >> 6;
    int wr = wid >> 1, wc = wid & 1;

    int sid = xcd_swz(blockIdx.x, gridDim.x);
    int p = sid % 5, bm = (sid / 5) * 128;
    int job = p < 2 ? 0 : 1;
    int bn = job ? (p - 2) * 128 : p * 128;
    const u16* A  = job ? qb : srcb;
    const u16* Bt = job ? woa_t : wv_t;

    f32x4 acc[4][4] = {};
    int srcslot = ((lane & 3) ^ ((lane >> 2) & 3) ^ ((lane >> 4) & 3)) << 3;
    int lrow = lane >> 2;

    auto stage = [&](int t) {
        int k0 = t * 32, sb = t % 3;
        #pragma unroll
        for (int c = 0; c < 2; ++c) {
            int rr = wid * 32 + c * 16 + lrow;
            int ra = bm + rr; ra = ra < N_TOK ? ra : N_TOK - 1;
            GLOAD16(A + (size_t)ra * 256 + k0 + srcslot,
                    (char*)As + sb * 8192 + wid * 2048 + c * 1024);
            GLOAD16(Bt + (size_t)(bn + rr) * 256 + k0 + srcslot,
                    (char*)Bs + sb * 8192 + wid * 2048 + c * 1024);
        }
    };

    stage(0); stage(1); stage(2);

    int rlo = lane & 15, khalf = lane >> 4;
    int fsl = ((khalf ^ (rlo & 3) ^ ((rlo >> 2) & 3)) << 3);

    for (int t = 0; t < 8; ++t) {
        if (t + 2 < 8)      asm volatile("s_waitcnt vmcnt(8)" ::: "memory");
        else if (t + 1 < 8) asm volatile("s_waitcnt vmcnt(4)" ::: "memory");
        else                asm volatile("s_waitcnt vmcnt(0)" ::: "memory");
        __builtin_amdgcn_s_barrier();
        __builtin_amdgcn_sched_barrier(0);

        const u16* a_lds = As + (t % 3) * 4096;
        const u16* b_lds = Bs + (t % 3) * 4096;
        short8 af[4], bf_[4];
        #pragma unroll
        for (int mi = 0; mi < 4; ++mi)
            af[mi] = *(const short8*)(a_lds + (wr * 64 + mi * 16 + rlo) * 32 + fsl);
        #pragma unroll
        for (int ni = 0; ni < 4; ++ni)
            bf_[ni] = *(const short8*)(b_lds + (wc * 64 + ni * 16 + rlo) * 32 + fsl);

        __builtin_amdgcn_s_setprio(1);
        #pragma unroll
        for (int mi = 0; mi < 4; ++mi)
            #pragma unroll
            for (int ni = 0; ni < 4; ++ni)
                acc[mi][ni] = __builtin_amdgcn_mfma_f32_16x16x32_bf16(
                    af[mi], bf_[ni], acc[mi][ni], 0, 0, 0);
        __builtin_amdgcn_s_setprio(0);

        __builtin_amdgcn_sched_barrier(0);
        asm volatile("s_waitcnt lgkmcnt(0)" ::: "memory");
        __builtin_amdgcn_s_barrier();
        if (t + 3 < 8) stage(t + 3);
    }

    int col_l = lane & 15, rgrp = lane >> 4;
    #pragma unroll
    for (int mi = 0; mi < 4; ++mi) {
        #pragma unroll
        for (int j = 0; j < 4; ++j) {
            int row = bm + wr * 64 + mi * 16 + rgrp * 4 + j;
            if (row >= N_TOK) continue;
            #pragma unroll
            for (int ni = 0; ni < 4; ++ni) {
                int col = bn + wc * 64 + ni * 16 + col_l;
                if (job) OA[(size_t)row * 384 + col] = acc[mi][ni][j] + boa[col];
                else     Vb[(size_t)row * 256 + col] = f2bf(acc[mi][ni][j] + b_value[col]);
            }
        }
    }
}

// ============ pipelined bf16 MFMA GEMM: 128x128 tile, BK=32, 3-deep (FFN1) ============
__global__ __launch_bounds__(256) void gemm2(
    const u16* __restrict__ A, const u16* __restrict__ Bt,
    const float* __restrict__ bias, float* __restrict__ Cf, u16* __restrict__ Cb,
    int M, int Nc, int K, int relu)
{
    __shared__ u16 As[3 * 4096];
    __shared__ u16 Bs[3 * 4096];
    int tid = threadIdx.x;
    int lane = tid & 63, wid = tid >> 6;
    int wr = wid >> 1, wc = wid & 1;

    int nwg = gridDim.x * gridDim.y;
    int sid = xcd_swz(blockIdx.y * gridDim.x + blockIdx.x, nwg);
    int bm = (sid / gridDim.x) * 128, bn = (sid % gridDim.x) * 128;

    f32x4 acc[4][4] = {};
    int srcslot = ((lane & 3) ^ ((lane >> 2) & 3) ^ ((lane >> 4) & 3)) << 3;
    int lrow = lane >> 2;

    auto stage = [&](int t) {
        int k0 = t * 32, sb = t % 3;
        #pragma unroll
        for (int c = 0; c < 2; ++c) {
            int rr = wid * 32 + c * 16 + lrow;
            int ra = bm + rr; ra = ra < M ? ra : M - 1;
            GLOAD16(A + (size_t)ra * K + k0 + srcslot,
                    (char*)As + sb * 8192 + wid * 2048 + c * 1024);
            GLOAD16(Bt + (size_t)(bn + rr) * K + k0 + srcslot,
                    (char*)Bs + sb * 8192 + wid * 2048 + c * 1024);
        }
    };

    int KT = K >> 5;
    stage(0); stage(1); stage(2);

    int rlo = lane & 15, khalf = lane >> 4;
    int fsl = ((khalf ^ (rlo & 3) ^ ((rlo >> 2) & 3)) << 3);

    for (int t = 0; t < KT; ++t) {
        if (t + 2 < KT)      asm volatile("s_waitcnt vmcnt(8)" ::: "memory");
        else if (t + 1 < KT) asm volatile("s_waitcnt vmcnt(4)" ::: "memory");
        else                 asm volatile("s_waitcnt vmcnt(0)" ::: "memory");
        __builtin_amdgcn_s_barrier();
        __builtin_amdgcn_sched_barrier(0);

        const u16* a_lds = As + (t % 3) * 4096;
        const u16* b_lds = Bs + (t % 3) * 4096;
        short8 af[4], bf_[4];
        #pragma unroll
        for (int mi = 0; mi < 4; ++mi)
            af[mi] = *(const short8*)(a_lds + (wr * 64 + mi * 16 + rlo) * 32 + fsl);
        #pragma unroll
        for (int ni = 0; ni < 4; ++ni)
            bf_[ni] = *(const short8*)(b_lds + (wc * 64 + ni * 16 + rlo) * 32 + fsl);

        __builtin_amdgcn_s_setprio(1);
        #pragma unroll
        for (int mi = 0; mi < 4; ++mi)
            #pragma unroll
            for (int ni = 0; ni < 4; ++ni)
                acc[mi][ni] = __builtin_amdgcn_mfma_f32_16x16x32_bf16(
                    af[mi], bf_[ni], acc[mi][ni], 0, 0, 0);
        __builtin_amdgcn_s_setprio(0);

        __builtin_amdgcn_sched_barrier(0);
        asm volatile("s_waitcnt lgkmcnt(0)" ::: "memory");
        __builtin_amdgcn_s_barrier();
        if (t + 3 < KT) stage(t + 3);
    }

    int col_l = lane & 15, rgrp = lane >> 4;
    #pragma unroll
    for (int mi = 0; mi < 4; ++mi) {
        #pragma unroll
        for (int j = 0; j < 4; ++j) {
            int row = bm + wr * 64 + mi * 16 + rgrp * 4 + j;
            if (row >= M) continue;
            #pragma unroll
            for (int ni = 0; ni < 4; ++ni) {
                int col = bn + wc * 64 + ni * 16 + col_l;
                float v = acc[mi][ni][j];
                if (bias) v += bias[col];
                if (relu) v = fmaxf(v, 0.f);
                if (Cf) Cf[(size_t)row * Nc + col] = v;
                if (Cb) Cb[(size_t)row * Nc + col] = f2bf(v);
            }
        }
    }
}

// ============ pipelined Nc=256 GEMM + residual + LayerNorm, BK=32, 3-deep ============
__global__ __launch_bounds__(256) void gemm_ln(
    const u16* __restrict__ A, const u16* __restrict__ Bt,
    const float* __restrict__ bias, const float* __restrict__ res,
    const float* __restrict__ g, const float* __restrict__ beta,
    float* __restrict__ outf, u16* __restrict__ outb,
    int M, int K)
{
    __shared__ u16 As[3 * 2048];
    __shared__ u16 Bs[3 * 8192];
    int tid = threadIdx.x;
    int lane = tid & 63, wc = tid >> 6;
    int bm = blockIdx.x * 64;
    f32x4 acc[4][4] = {};
    int srcslot = ((lane & 3) ^ ((lane >> 2) & 3) ^ ((lane >> 4) & 3)) << 3;
    int lrow = lane >> 2;

    auto stage = [&](int t) {
        int k0 = t * 32, sb = t % 3;
        int ra = bm + wc * 16 + lrow; ra = ra < M ? ra : M - 1;
        GLOAD16(A + (size_t)ra * K + k0 + srcslot,
                (char*)As + sb * 4096 + wc * 1024);
        #pragma unroll
        for (int i = 0; i < 4; ++i) {
            int cc = i * 64 + wc * 16 + lrow;
            GLOAD16(Bt + (size_t)cc * K + k0 + srcslot,
                    (char*)Bs + sb * 16384 + i * 4096 + wc * 1024);
        }
    };

    int KT = K >> 5;
    stage(0); stage(1); stage(2);

    int rlo = lane & 15, khalf = lane >> 4;
    int fsl = ((khalf ^ (rlo & 3) ^ ((rlo >> 2) & 3)) << 3);

    for (int t = 0; t < KT; ++t) {
        if (t + 2 < KT)      asm volatile("s_waitcnt vmcnt(10)" ::: "memory");
        else if (t + 1 < KT) asm volatile("s_waitcnt vmcnt(5)" ::: "memory");
        else                 asm volatile("s_waitcnt vmcnt(0)" ::: "memory");
        __builtin_amdgcn_s_barrier();
        __builtin_amdgcn_sched_barrier(0);

        const u16* a_lds = As + (t % 3) * 2048;
        const u16* b_lds = Bs + (t % 3) * 8192;
        short8 af[4], bf_[4];
        #pragma unroll
        for (int mi = 0; mi < 4; ++mi)
            af[mi] = *(const short8*)(a_lds + (mi * 16 + rlo) * 32 + fsl);
        #pragma unroll
        for (int ni = 0; ni < 4; ++ni)
            bf_[ni] = *(const short8*)(b_lds + (wc * 64 + ni * 16 + rlo) * 32 + fsl);

        __builtin_amdgcn_s_setprio(1);
        #pragma unroll
        for (int mi = 0; mi < 4; ++mi)
            #pragma unroll
            for (int ni = 0; ni < 4; ++ni)
                acc[mi][ni] = __builtin_amdgcn_mfma_f32_16x16x32_bf16(
                    af[mi], bf_[ni], acc[mi][ni], 0, 0, 0);
        __builtin_amdgcn_s_setprio(0);

        __builtin_amdgcn_sched_barrier(0);
        asm volatile("s_waitcnt lgkmcnt(0)" ::: "memory");
        __builtin_amdgcn_s_barrier();
        if (t + 3 < KT) stage(t + 3);
    }
    __syncthreads();

    float* red = (float*)As;
    int col_l = lane & 15, rgrp = lane >> 4;
    int colc[4]; float bias_c[4], g_c[4], be_c[4];
    #pragma unroll
    for (int ni = 0; ni < 4; ++ni) {
        colc[ni] = wc * 64 + ni * 16 + col_l;
        bias_c[ni] = bias[colc[ni]];
        g_c[ni]  = g[colc[ni]];
        be_c[ni] = beta[colc[ni]];
    }
    #pragma unroll
    for (int mi = 0; mi < 4; ++mi) {
        #pragma unroll
        for (int j = 0; j < 4; ++j) {
            int rl = mi * 16 + rgrp * 4 + j;
            int row = bm + rl;
            float s = 0.f, s2 = 0.f;
            if (row < M) {
                #pragma unroll
                for (int ni = 0; ni < 4; ++ni) {
                    float v = acc[mi][ni][j] + bias_c[ni] + res[(size_t)row * 256 + colc[ni]];
                    acc[mi][ni][j] = v;
                    s += v; s2 += v * v;
                }
            }
            #pragma unroll
            for (int d = 1; d < 16; d <<= 1) { s += __shfl_xor(s, d); s2 += __shfl_xor(s2, d); }
            if (col_l == 0) { red[wc * 64 + rl] = s; red[256 + wc * 64 + rl] = s2; }
        }
    }
    __syncthreads();
    if (tid < 64) {
        float s  = red[tid] + red[64 + tid] + red[128 + tid] + red[192 + tid];
        float s2 = red[256 + tid] + red[320 + tid] + red[384 + tid] + red[448 + tid];
        float mean = s * (1.f / 256.f);
        float var = s2 * (1.f / 256.f) - mean * mean;
        red[512 + tid] = mean;
        red[576 + tid] = rsqrtf(var + 1e-5f);
    }
    __syncthreads();
    #pragma unroll
    for (int mi = 0; mi < 4; ++mi) {
        #pragma unroll
        for (int j = 0; j < 4; ++j) {
            int rl = mi * 16 + rgrp * 4 + j;
            int row = bm + rl;
            if (row >= M) continue;
            float mean = red[512 + rl], rs = red[576 + rl];
            #pragma unroll
            for (int ni = 0; ni < 4; ++ni) {
                float o = g_c[ni] * (acc[mi][ni][j] - mean) * rs + be_c[ni];
                outf[(size_t)row * 256 + colc[ni]] = o;
                if (outb) outb[(size_t)row * 256 + colc[ni]] = f2bf(o);
            }
        }
    }
}

// ---- deformable sampling: 2 waves per token (4 heads each), no inter-wave sync ----
// Each wave computes the 64 (h,pt) records for ITS 4 heads (phase 1), then gathers
// them (phase 2). Lane = h_local*16 + dq; lane owns 2 dims (dword gathers).
__global__ __launch_bounds__(256) void ms_sample(
    const u16* __restrict__ value, const float* __restrict__ oa,
    const float* __restrict__ refp, u16* __restrict__ out)
{
    const int starts[4] = {0, 8464, 10580, 11109};
    const int sizes[4]  = {92, 46, 23, 12};
    int t = threadIdx.x;
    int wid = t >> 6, lane = t & 63;
    int wv2 = wid >> 1;          // token slot in block (0,1)
    int wpar = wid & 1;          // head-half parity
    int n = blockIdx.x * 2 + wv2;   // grid = N_TOK/2 exactly (22506 even)

    __shared__ uint4  s_ad[2][128];
    __shared__ float4 s_wt[2][128];

    const float* oan = oa + (size_t)n * 384;
    unsigned int tokbase = (n >= LEN) ? (unsigned)LEN : 0u;
    {
        int q = wpar * 64 + lane;         // q = h*16 + pt ; h in [wpar*4, wpar*4+4)
        int h = q >> 4, pt = q & 15, l = pt >> 2;
        float logit = oan[256 + q];
        float m = logit;
        #pragma unroll
        for (int d = 1; d < 16; d <<= 1) m = fmaxf(m, __shfl_xor(m, d));
        float e = __expf(logit - m);
        float ssum = e;
        #pragma unroll
        for (int d = 1; d < 16; d <<= 1) ssum += __shfl_xor(ssum, d);
        float aw = e / ssum;
        float2 off2 = *(const float2*)(oan + 2 * q);
        float2 ref2 = *(const float2*)(refp + (size_t)n * 8 + l * 2);
        int wl = sizes[l];
        float wf = (float)wl;
        float x = ref2.x * wf - 0.5f + off2.x;
        float y = ref2.y * wf - 0.5f + off2.y;
        float x0f = floorf(x), y0f = floorf(y);
        float fx = x - x0f, fy = y - y0f;
        int x0 = (int)x0f, y0 = (int)y0f;
        int x1 = x0 + 1, y1 = y0 + 1;
        float gx = 1.f - fx, gy = 1.f - fy;
        bool bx0 = (unsigned)x0 < (unsigned)wl, bx1 = (unsigned)x1 < (unsigned)wl;
        bool by0 = (unsigned)y0 < (unsigned)wl, by1 = (unsigned)y1 < (unsigned)wl;
        float w00 = (bx0 && by0) ? gx * gy * aw : 0.f;
        float w10 = (bx1 && by0) ? fx * gy * aw : 0.f;
        float w01 = (bx0 && by1) ? gx * fy * aw : 0.f;
        float w11 = (bx1 && by1) ? fx * fy * aw : 0.f;
        int x0c = min(max(x0, 0), wl - 1), x1c = min(max(x1, 0), wl - 1);
        int y0c = min(max(y0, 0), wl - 1), y1c = min(max(y1, 0), wl - 1);
        unsigned int base = (tokbase + (unsigned)starts[l]) * 512u + (unsigned)(h * 64);
        unsigned int r0 = base + (unsigned)(y0c * wl) * 512u;
        unsigned int r1 = base + (unsigned)(y1c * wl) * 512u;
        int idx = pt * 8 + (h ^ (pt & 7));
        s_ad[wv2][idx] = make_uint4(r0 + (unsigned)x0c * 512u, r0 + (unsigned)x1c * 512u,
                                    r1 + (unsigned)x0c * 512u, r1 + (unsigned)x1c * 512u);
        s_wt[wv2][idx] = make_float4(w00, w10, w01, w11);
    }
    // records are read back ONLY by the wave that wrote them -> no barrier needed
    asm volatile("s_waitcnt lgkmcnt(0)" ::: "memory");

    int h = wpar * 4 + (lane >> 4);   // this lane's head
    int dq = lane & 15;               // dim-pair index (2 dims, 4 bytes)
    const char* vb = (const char*)value + dq * 4;

    // 3-slot pipelined dword gathers; 4 independent acc chains
    unsigned int v00[3], v10[3], v01[3], v11[3];
    float4 wt[3];
    f32x2 c0 = {0,0}, c1 = {0,0}, c2 = {0,0}, c3 = {0,0};

    #pragma unroll
    for (int pt = 0; pt < 3; ++pt) {
        int idx = pt * 8 + (h ^ (pt & 7));
        uint4 ad = s_ad[wv2][idx];
        wt[pt] = s_wt[wv2][idx];
        v00[pt] = *(const unsigned int*)(vb + ad.x);
        v10[pt] = *(const unsigned int*)(vb + ad.y);
        v01[pt] = *(const unsigned int*)(vb + ad.z);
        v11[pt] = *(const unsigned int*)(vb + ad.w);
    }
    #pragma unroll
    for (int pt = 0; pt < 16; ++pt) {
        int s = pt % 3;
        c0 += wt[s].x * bf2x2(v00[s]);
        c1 += wt[s].y * bf2x2(v10[s]);
        c2 += wt[s].z * bf2x2(v01[s]);
        c3 += wt[s].w * bf2x2(v11[s]);
        if (pt + 3 < 16) {
            int np = pt + 3;
            int idx = np * 8 + (h ^ (np & 7));
            uint4 ad = s_ad[wv2][idx];
            wt[s] = s_wt[wv2][idx];
            v00[s] = *(const unsigned int*)(vb + ad.x);
            v10[s] = *(const unsigned int*)(vb + ad.y);
            v01[s] = *(const unsigned int*)(vb + ad.z);
            v11[s] = *(const unsigned int*)(vb + ad.w);
        }
    }
    f32x2 a01 = (c0 + c1) + (c2 + c3);
    u16 o[2] = { f2bf(a01[0]), f2bf(a01[1]) };
    *(ushort2*)(out + (size_t)n * 256 + h * 32 + dq * 2) = *(ushort2*)o;
}

extern "C" void kernel_launch(void* const* d_in, const int* in_sizes, int n_in,
                              void* d_out, int out_size, void* d_ws, size_t ws_size,
                              hipStream_t stream) {
    const float* src    = (const float*)d_in[0];
    const float* pos    = (const float*)d_in[1];
    const float* refp   = (const float*)d_in[2];
    const float* w_value= (const float*)d_in[3];
    const float* b_value= (const float*)d_in[4];
    const float* w_off  = (const float*)d_in[5];
    const float* b_off  = (const float*)d_in[6];
    const float* w_attn = (const float*)d_in[7];
    const float* b_attn = (const float*)d_in[8];
    const float* w_out  = (const float*)d_in[9];
    const float* b_out  = (const float*)d_in[10];
    const float* ln1_g  = (const float*)d_in[11];
    const float* ln1_b  = (const float*)d_in[12];
    const float* w1     = (const float*)d_in[13];
    const float* b1     = (const float*)d_in[14];
    const float* w2     = (const float*)d_in[15];
    const float* b2     = (const float*)d_in[16];
    const float* ln2_g  = (const float*)d_in[17];
    const float* ln2_b  = (const float*)d_in[18];

    // ws layout (bytes), liveness-packed:
    //   srcb [0, 11523072)         bf16; dead after gemm5; then Sb
    //   Vb   [11523072, 23046144)  bf16; dead after sample
    //   qb   [23046144, 34569216)  bf16; dead after gemm5
    //   X    [11523072, 34569216)  f32  LN1 out (overlay)
    //   OA   [34569216, 69138432)  f32; dead after sample
    //   Xb   [34569216, 46092288)  bf16 LN1 out (overlay)
    //   Hb   [46092288, 92184576)  bf16 FFN hidden
    //   weights [92184576, ...)
    char* w = (char*)d_ws;
    u16*   srcb = (u16*)w;
    u16*   Sb   = srcb;
    u16*   Vb   = (u16*)(w + 11523072);
    u16*   qb   = (u16*)(w + 23046144);
    float* X    = (float*)(w + 11523072);
    float* OA   = (float*)(w + 34569216);
    u16*   Xb   = (u16*)(w + 34569216);
    u16*   Hb   = (u16*)(w + 46092288);
    char*  WB   = w + 92184576;
    u16* wv_t   = (u16*)WB;
    u16* woa_t  = wv_t + 65536;
    u16* wout_t = woa_t + 98304;
    u16* w1_t   = wout_t + 65536;
    u16* w2_t   = w1_t + 262144;
    float* boa  = (float*)(w2_t + 262144);
    float* out  = (float*)d_out;

    dim3 b256(256);
    int MB = (N_TOK + 127) / 128;   // 176

    wprep<<<dim3(8572), b256, 0, stream>>>(w_value, w_off, w_attn, w_out, w1, w2,
                                           b_off, b_attn, src, pos,
                                           wv_t, woa_t, wout_t, w1_t, w2_t, boa, srcb, qb);
    gemm5<<<dim3(5 * MB), b256, 0, stream>>>(srcb, qb, wv_t, woa_t, b_value, boa, Vb, OA);
    ms_sample<<<dim3(N_TOK / 2), b256, 0, stream>>>(Vb, OA, refp, Sb);
    gemm_ln<<<dim3((N_TOK + 63) / 64), b256, 0, stream>>>(Sb, wout_t, b_out, src,
                                                          ln1_g, ln1_b, X, Xb, N_TOK, 256);
    gemm2<<<dim3(8, MB), b256, 0, stream>>>(Xb, w1_t, b1, nullptr, Hb, N_TOK, 1024, 256, 1);
    gemm_ln<<<dim3((N_TOK + 63) / 64), b256, 0, stream>>>(Hb, w2_t, b2, X,
                                                          ln2_g, ln2_b, out, nullptr, N_TOK, 1024);
}